// Round 11
// baseline (322.357 us; speedup 1.0000x reference)
//
#include <hip/hip_runtime.h>
#include <math.h>

#define N_NODES 16384
#define B_GRAPHS 8
#define NPG_     2048
#define E_EDGES  262144
#define F_IN  128
#define F_HID 256
#define F_OUT 128
#define ICP_IT 10

typedef __attribute__((ext_vector_type(8))) short bf16x8;
typedef __attribute__((ext_vector_type(4))) float f32x4;

__device__ __forceinline__ float b2f(unsigned short u) {
    union { unsigned int u; float f; } v; v.u = ((unsigned int)u) << 16; return v.f;
}
__device__ __forceinline__ unsigned short f2b(float f) {
    union { float f; unsigned int u; } v; v.f = f;
    unsigned int r = v.u + 0x7FFFu + ((v.u >> 16) & 1u);
    return (unsigned short)(r >> 16);
}
// XOR swizzle within 32-element groups: spreads lane-sliced LDS scans over banks.
__device__ __forceinline__ int swz32(int i) {
    return (i & ~31) | ((i & 31) ^ ((i >> 5) & 31));
}
// Agent-scope accesses (device-coherent; validated R4-R10 pattern).
__device__ __forceinline__ void st_agent(float* p, float v) {
    __hip_atomic_store(p, v, __ATOMIC_RELAXED, __HIP_MEMORY_SCOPE_AGENT);
}
__device__ __forceinline__ float ld_agent(const float* p) {
    return __hip_atomic_load(p, __ATOMIC_RELAXED, __HIP_MEMORY_SCOPE_AGENT);
}
__device__ __forceinline__ void st_agent_i(int* p, int v) {
    __hip_atomic_store(p, v, __ATOMIC_RELAXED, __HIP_MEMORY_SCOPE_AGENT);
}
__device__ __forceinline__ int ld_agent_i(const int* p) {
    return __hip_atomic_load(p, __ATOMIC_RELAXED, __HIP_MEMORY_SCOPE_AGENT);
}

// ------- k_prep: x->bf16, weight transpose-converts, edge count (counts/partials/ctrs
// pre-zeroed by one stream-ordered memset) -------------------------------------------------
__global__ __launch_bounds__(256) void k_prep(
    const float* __restrict__ x, unsigned short* __restrict__ xb,
    const float* __restrict__ W1, const float* __restrict__ W2, const float* __restrict__ W3,
    unsigned short* __restrict__ W1b, unsigned short* __restrict__ W2b, unsigned short* __restrict__ W3b,
    const int* __restrict__ col, int* __restrict__ counts)
{
    const int b = blockIdx.x, tid = threadIdx.x;
    if (b < 2048) {                       // x: 524288 float4 -> uint2
        int i = b * 256 + tid;
        float4 v = ((const float4*)x)[i];
        uint2 o;
        o.x = (unsigned int)f2b(v.x) | ((unsigned int)f2b(v.y) << 16);
        o.y = (unsigned int)f2b(v.z) | ((unsigned int)f2b(v.w) << 16);
        ((uint2*)xb)[i] = o;
    } else if (b < 2176) {                // W1 [128][256] -> W1b [256][128]
        int idx = (b - 2048) * 256 + tid;
        int k = idx >> 8, n = idx & 255;
        W1b[n * 128 + k] = f2b(W1[idx]);
    } else if (b < 2432) {                // W2 [256][256] -> W2b [256][256]
        int idx = (b - 2176) * 256 + tid;
        int k = idx >> 8, n = idx & 255;
        W2b[n * 256 + k] = f2b(W2[idx]);
    } else if (b < 2560) {                // W3 [256][128] -> W3b [128][256]
        int idx = (b - 2432) * 256 + tid;
        int k = idx >> 7, n = idx & 127;
        W3b[n * 256 + k] = f2b(W3[idx]);
    } else {                              // edge in-degree count
        int e = (b - 2560) * 256 + tid;
        atomicAdd(&counts[col[e]], 1);
    }
}

// ---------------- CSR build ----------------
__global__ __launch_bounds__(1024) void k_scan(const int* __restrict__ counts,
        int* __restrict__ offs, int* __restrict__ cursor, float* __restrict__ dinv)
{
    __shared__ int wtot[16];
    const int t = threadIdx.x;
    const int base = t * 16;
    int local[16];
    int s = 0;
#pragma unroll
    for (int i = 0; i < 16; i++) { local[i] = counts[base + i]; s += local[i]; }
    const int lane = t & 63, w = t >> 6;
    int inc = s;                        // inclusive wave scan
    for (int o = 1; o < 64; o <<= 1) {
        int v = __shfl_up(inc, o);
        if (lane >= o) inc += v;
    }
    if (lane == 63) wtot[w] = inc;
    __syncthreads();
    if (t < 16) {
        int v = wtot[t];
        for (int o = 1; o < 16; o <<= 1) {
            int u = __shfl_up(v, o);
            if (t >= o) v += u;
        }
        wtot[t] = v;
    }
    __syncthreads();
    int run = (w > 0 ? wtot[w - 1] : 0) + (inc - s);
#pragma unroll
    for (int i = 0; i < 16; i++) {
        offs[base + i]   = run;
        cursor[base + i] = run;
        dinv[base + i]   = rsqrtf((float)(local[i] + 1));  // deg = indeg + self loop
        run += local[i];
    }
    if (t == 1023) offs[N_NODES] = run;
}

__global__ void k_scatter(const int* __restrict__ row, const int* __restrict__ col,
        int* __restrict__ cursor, const float* __restrict__ dinv,
        int* __restrict__ srcid, float* __restrict__ normv)
{
    int e = blockIdx.x * 256 + threadIdx.x;
    if (e >= E_EDGES) return;
    int r = row[e], c = col[e];
    int p = atomicAdd(&cursor[c], 1);
    srcid[p] = r;
    normv[p] = dinv[r] * dinv[c];
}

// ---------------- GCN aggregation W=128 (bf16 in, fp32 acc); unroll-4; fused tpos ---------
template<int OUTF, int FUSET>
__global__ __launch_bounds__(128) void k_agg128(const unsigned short* __restrict__ X,
        void* __restrict__ Y,
        const int* __restrict__ offs, const int* __restrict__ srcid,
        const float* __restrict__ normv, const float* __restrict__ dinv,
        const float* __restrict__ bias, int relu,
        const float* __restrict__ Wt, const float* __restrict__ bt,
        const float* __restrict__ pos, float* __restrict__ tposO)
{
    const int local = threadIdx.x >> 6;
    const int n = blockIdx.x * 2 + local;
    const int j = threadIdx.x & 63;
    const unsigned int* Xu = (const unsigned int*)X;
    float di = dinv[n];
    float w0 = di * di;
    unsigned int v = Xu[(size_t)n * 64 + j];
    float a0 = b2f((unsigned short)v) * w0;
    float a1 = b2f((unsigned short)(v >> 16)) * w0;
    int p = offs[n];
    const int p1 = offs[n + 1];
    for (; p + 3 < p1; p += 4) {
        int s0i = srcid[p], s1i = srcid[p + 1], s2i = srcid[p + 2], s3i = srcid[p + 3];
        float n0 = normv[p], n1 = normv[p + 1], n2 = normv[p + 2], n3 = normv[p + 3];
        unsigned int v0 = Xu[(size_t)s0i * 64 + j];
        unsigned int v1 = Xu[(size_t)s1i * 64 + j];
        unsigned int v2 = Xu[(size_t)s2i * 64 + j];
        unsigned int v3 = Xu[(size_t)s3i * 64 + j];
        a0 = fmaf(b2f((unsigned short)v0), n0, a0);
        a1 = fmaf(b2f((unsigned short)(v0 >> 16)), n0, a1);
        a0 = fmaf(b2f((unsigned short)v1), n1, a0);
        a1 = fmaf(b2f((unsigned short)(v1 >> 16)), n1, a1);
        a0 = fmaf(b2f((unsigned short)v2), n2, a0);
        a1 = fmaf(b2f((unsigned short)(v2 >> 16)), n2, a1);
        a0 = fmaf(b2f((unsigned short)v3), n3, a0);
        a1 = fmaf(b2f((unsigned short)(v3 >> 16)), n3, a1);
    }
    for (; p < p1; ++p) {
        unsigned int va = Xu[(size_t)srcid[p] * 64 + j]; float na = normv[p];
        a0 = fmaf(b2f((unsigned short)va), na, a0);
        a1 = fmaf(b2f((unsigned short)(va >> 16)), na, a1);
    }
    if (bias) { a0 += bias[2 * j]; a1 += bias[2 * j + 1]; }
    if (relu) { a0 = fmaxf(a0, 0.f); a1 = fmaxf(a1, 0.f); }
    if (OUTF) {
        float* Yf = (float*)Y;
        Yf[(size_t)n * 128 + 2 * j]     = a0;
        Yf[(size_t)n * 128 + 2 * j + 1] = a1;
    } else {
        ((unsigned int*)Y)[(size_t)n * 64 + j] =
            (unsigned int)f2b(a0) | ((unsigned int)f2b(a1) << 16);
    }
    if (FUSET) {   // tpos = pos + h @ Wt + bt, wave-per-node
        float wt0 = Wt[6 * j + 0], wt1 = Wt[6 * j + 1], wt2 = Wt[6 * j + 2];
        float wt3 = Wt[6 * j + 3], wt4 = Wt[6 * j + 4], wt5 = Wt[6 * j + 5];
        float s0 = a0 * wt0 + a1 * wt3;
        float s1 = a0 * wt1 + a1 * wt4;
        float s2 = a0 * wt2 + a1 * wt5;
        for (int o = 32; o > 0; o >>= 1) {
            s0 += __shfl_down(s0, o);
            s1 += __shfl_down(s1, o);
            s2 += __shfl_down(s2, o);
        }
        if (j == 0) {
            tposO[n * 3 + 0] = pos[n * 3 + 0] + s0 + bt[0];
            tposO[n * 3 + 1] = pos[n * 3 + 1] + s1 + bt[1];
            tposO[n * 3 + 2] = pos[n * 3 + 2] + s2 + bt[2];
        }
    }
}

// ---------------- GCN aggregation W=256: one wave per node, uint2 (4 cols/lane) -----------
__global__ __launch_bounds__(128) void k_agg256(const unsigned short* __restrict__ X,
        unsigned short* __restrict__ Y,
        const int* __restrict__ offs, const int* __restrict__ srcid,
        const float* __restrict__ normv, const float* __restrict__ dinv,
        const float* __restrict__ bias, int relu)
{
    const int local = threadIdx.x >> 6;
    const int n = blockIdx.x * 2 + local;
    const int lane = threadIdx.x & 63;
    const uint2* Xu = (const uint2*)X;      // 64 uint2 per 256-wide row
    float di = dinv[n];
    float w0 = di * di;
    uint2 v = Xu[(size_t)n * 64 + lane];
    float a0 = b2f((unsigned short)v.x) * w0;
    float a1 = b2f((unsigned short)(v.x >> 16)) * w0;
    float a2 = b2f((unsigned short)v.y) * w0;
    float a3 = b2f((unsigned short)(v.y >> 16)) * w0;
    int p = offs[n];
    const int p1 = offs[n + 1];
    for (; p + 3 < p1; p += 4) {
        int s0i = srcid[p], s1i = srcid[p + 1], s2i = srcid[p + 2], s3i = srcid[p + 3];
        float n0 = normv[p], n1 = normv[p + 1], n2 = normv[p + 2], n3 = normv[p + 3];
        uint2 v0 = Xu[(size_t)s0i * 64 + lane];
        uint2 v1 = Xu[(size_t)s1i * 64 + lane];
        uint2 v2 = Xu[(size_t)s2i * 64 + lane];
        uint2 v3 = Xu[(size_t)s3i * 64 + lane];
        a0 = fmaf(b2f((unsigned short)v0.x), n0, a0);
        a1 = fmaf(b2f((unsigned short)(v0.x >> 16)), n0, a1);
        a2 = fmaf(b2f((unsigned short)v0.y), n0, a2);
        a3 = fmaf(b2f((unsigned short)(v0.y >> 16)), n0, a3);
        a0 = fmaf(b2f((unsigned short)v1.x), n1, a0);
        a1 = fmaf(b2f((unsigned short)(v1.x >> 16)), n1, a1);
        a2 = fmaf(b2f((unsigned short)v1.y), n1, a2);
        a3 = fmaf(b2f((unsigned short)(v1.y >> 16)), n1, a3);
        a0 = fmaf(b2f((unsigned short)v2.x), n2, a0);
        a1 = fmaf(b2f((unsigned short)(v2.x >> 16)), n2, a1);
        a2 = fmaf(b2f((unsigned short)v2.y), n2, a2);
        a3 = fmaf(b2f((unsigned short)(v2.y >> 16)), n2, a3);
        a0 = fmaf(b2f((unsigned short)v3.x), n3, a0);
        a1 = fmaf(b2f((unsigned short)(v3.x >> 16)), n3, a1);
        a2 = fmaf(b2f((unsigned short)v3.y), n3, a2);
        a3 = fmaf(b2f((unsigned short)(v3.y >> 16)), n3, a3);
    }
    for (; p < p1; ++p) {
        uint2 va = Xu[(size_t)srcid[p] * 64 + lane]; float na = normv[p];
        a0 = fmaf(b2f((unsigned short)va.x), na, a0);
        a1 = fmaf(b2f((unsigned short)(va.x >> 16)), na, a1);
        a2 = fmaf(b2f((unsigned short)va.y), na, a2);
        a3 = fmaf(b2f((unsigned short)(va.y >> 16)), na, a3);
    }
    if (bias) {
        float4 bv = ((const float4*)bias)[lane];
        a0 += bv.x; a1 += bv.y; a2 += bv.z; a3 += bv.w;
    }
    if (relu) {
        a0 = fmaxf(a0, 0.f); a1 = fmaxf(a1, 0.f);
        a2 = fmaxf(a2, 0.f); a3 = fmaxf(a3, 0.f);
    }
    uint2 o;
    o.x = (unsigned int)f2b(a0) | ((unsigned int)f2b(a1) << 16);
    o.y = (unsigned int)f2b(a2) | ((unsigned int)f2b(a3) << 16);
    ((uint2*)Y)[(size_t)n * 64 + lane] = o;
}

// ---------------- bf16 MFMA GEMM: C[M,N] = A[M,K] @ Bt[N,K]^T (+bias,relu) ----------------
__global__ __launch_bounds__(256) void k_gemm_bf16(
    const unsigned short* __restrict__ A,   // [M][K] bf16
    const unsigned short* __restrict__ Bt,  // [N][K] bf16
    const float* __restrict__ bias, unsigned short* __restrict__ C,
    int M, int N, int K, int relu)
{
    __shared__ __align__(16) unsigned short As[128 * 64];
    __shared__ __align__(16) unsigned short Bs[64 * 64];
    const int tid  = threadIdx.x;
    const int lane = tid & 63;
    const int wave = tid >> 6;
    const int bm = blockIdx.y * 128, bn = blockIdx.x * 64;
    const int wm = (wave >> 1) * 64, wn = (wave & 1) * 32;
    f32x4 acc[4][2];
#pragma unroll
    for (int mf = 0; mf < 4; mf++)
#pragma unroll
        for (int nf = 0; nf < 2; nf++) acc[mf][nf] = (f32x4){0.f, 0.f, 0.f, 0.f};

    for (int k0 = 0; k0 < K; k0 += 64) {
#pragma unroll
        for (int i = 0; i < 4; i++) {
            int idx = i * 256 + tid;
            int m = idx >> 3, slot = idx & 7;
            const unsigned short* src = A + (size_t)(bm + m) * K + k0 + ((slot ^ (m & 7)) << 3);
            __builtin_amdgcn_global_load_lds(
                (const __attribute__((address_space(1))) unsigned int*)src,
                (__attribute__((address_space(3))) unsigned int*)(As + (size_t)i * 2048 + wave * 512),
                16, 0, 0);
        }
#pragma unroll
        for (int i = 0; i < 2; i++) {
            int idx = i * 256 + tid;
            int n = idx >> 3, slot = idx & 7;
            const unsigned short* src = Bt + (size_t)(bn + n) * K + k0 + ((slot ^ (n & 7)) << 3);
            __builtin_amdgcn_global_load_lds(
                (const __attribute__((address_space(1))) unsigned int*)src,
                (__attribute__((address_space(3))) unsigned int*)(Bs + (size_t)i * 2048 + wave * 512),
                16, 0, 0);
        }
        __syncthreads();
        bf16x8 af[4][2], bfr[2][2];
        const int qd = lane >> 4;
#pragma unroll
        for (int s = 0; s < 2; s++) {
#pragma unroll
            for (int mf = 0; mf < 4; mf++) {
                int m = wm + mf * 16 + (lane & 15);
                int slot = (s * 4 + qd) ^ (m & 7);
                af[mf][s] = *(const bf16x8*)(As + m * 64 + slot * 8);
            }
#pragma unroll
            for (int nf = 0; nf < 2; nf++) {
                int n = wn + nf * 16 + (lane & 15);
                int slot = (s * 4 + qd) ^ (n & 7);
                bfr[nf][s] = *(const bf16x8*)(Bs + n * 64 + slot * 8);
            }
        }
#pragma unroll
        for (int s = 0; s < 2; s++)
#pragma unroll
            for (int mf = 0; mf < 4; mf++)
#pragma unroll
                for (int nf = 0; nf < 2; nf++)
                    acc[mf][nf] = __builtin_amdgcn_mfma_f32_16x16x32_bf16(
                        af[mf][s], bfr[nf][s], acc[mf][nf], 0, 0, 0);
        __syncthreads();
    }
#pragma unroll
    for (int nf = 0; nf < 2; nf++) {
        int col = bn + wn + nf * 16 + (lane & 15);
        float bv = bias ? bias[col] : 0.f;
#pragma unroll
        for (int mf = 0; mf < 4; mf++) {
#pragma unroll
            for (int r = 0; r < 4; r++) {
                int row = bm + wm + mf * 16 + (lane >> 4) * 4 + r;
                float v = acc[mf][nf][r] + bv;
                if (relu) v = fmaxf(v, 0.f);
                C[(size_t)row * N + col] = f2b(v);
            }
        }
    }
}

// ---------------- persistent ICP (10 iters) + chamfer + loss, ONE launch ------------------
// R10 base (256 blocks x 512 thr, per-line tags, double-buffered partials). NEW: the whole
// post-scan sequence (argmin -> publish -> s_waitcnt -> tag -> per-line poll+fetch ->
// shuffle-tree sum -> SVD) runs inside wave 0 -- 2 barriers/iter instead of 6, and each
// partial line is fetched the moment ITS tag is ready (straggler-overlapped gather).
// XCD-affinity: g = blockIdx&7 groups a graph's 32 blocks on one XCD (perf heuristic only).
__global__ __launch_bounds__(512) void k_icp_all(
    const float* __restrict__ tpos, const float* __restrict__ pos,
    float* __restrict__ partials,   // [2][256][16]; slot15 = iteration tag (zeroed per call)
    float* __restrict__ chpart,     // [256][2]
    int* __restrict__ ctrs,         // [128]=chamfer arrival (zeroed per call)
    float* __restrict__ out_aligned, float* __restrict__ out_loss)
{
    const int g = blockIdx.x & 7, blk = blockIdx.x >> 3;
    const int myline = g * 32 + blk;
    const int tid = threadIdx.x;
    const int wave = tid >> 6, lane = tid & 63;
    __shared__ float4 tq[NPG_];                                // 32KB, swizzled, w=|t|^2
    __shared__ __align__(16) unsigned char scratch[NPG_ * 16]; // 32KB union (sm_d/sm_i | al)
    float* sm_d = (float*)scratch;                             // [64][65]
    unsigned short* sm_i = (unsigned short*)(scratch + 64 * 65 * 4);
    float4* al = (float4*)scratch;                             // chamfer phase only
    __shared__ float ssx[64], ssy[64], ssz[64];
    __shared__ float wred[8][2];
    __shared__ float Tsh[12];
    __shared__ int lastFlag;

    for (int i = tid; i < NPG_; i += 512) {
        const float* p = &pos[(size_t)(g * NPG_ + i) * 3];
        float qx = p[0], qy = p[1], qz = p[2];
        tq[swz32(i)] = make_float4(qx, qy, qz, fmaf(qx, qx, fmaf(qy, qy, qz * qz)));
    }
    if (tid < 12) Tsh[tid] = (tid == 0 || tid == 4 || tid == 8) ? 1.f : 0.f;
    // own 64 source points (8 per wave) in registers for all 10 iterations
    float Px[8], Py[8], Pz[8];
#pragma unroll
    for (int u = 0; u < 8; u++) {
        int n = g * NPG_ + blk * 64 + wave * 8 + u;
        Px[u] = tpos[n * 3 + 0]; Py[u] = tpos[n * 3 + 1]; Pz[u] = tpos[n * 3 + 2];
    }
    double Td[12];
    if (tid == 0) {
#pragma unroll
        for (int k = 0; k < 12; k++) Td[k] = (k == 0 || k == 4 || k == 8) ? 1.0 : 0.0;
    }
    __syncthreads();

    for (int iter = 0; iter < ICP_IT; ++iter) {
        const int bufbase = (iter & 1) * 256;
        float Tf[12];
#pragma unroll
        for (int k = 0; k < 12; k++) Tf[k] = Tsh[k];
        float Sx[8], Sy[8], Sz[8], Tx[8], Ty[8], Tz[8], bd[8];
        int bi[8];
#pragma unroll
        for (int u = 0; u < 8; u++) {
            float X = Tf[0] * Px[u] + Tf[1] * Py[u] + Tf[2] * Pz[u] + Tf[9];
            float Y = Tf[3] * Px[u] + Tf[4] * Py[u] + Tf[5] * Pz[u] + Tf[10];
            float Z = Tf[6] * Px[u] + Tf[7] * Py[u] + Tf[8] * Pz[u] + Tf[11];
            Sx[u] = X; Sy[u] = Y; Sz[u] = Z;
            Tx[u] = -2.f * X; Ty[u] = -2.f * Y; Tz[u] = -2.f * Z;
            bd[u] = 1e30f; bi[u] = lane * 32;
        }
        const int qbase = lane * 32;
        for (int j = 0; j < 32; j++) {
            float4 t4 = tq[qbase + (j ^ (lane & 31))];
            int idx = qbase + j;
#pragma unroll
            for (int u = 0; u < 8; u++) {
                // d' = |t|^2 - 2 s.t  (monotone in true distance)
                float d = fmaf(Tx[u], t4.x, fmaf(Ty[u], t4.y, fmaf(Tz[u], t4.z, t4.w)));
                if (d < bd[u]) { bd[u] = d; bi[u] = idx; }
            }
        }
        // stage candidates + transformed src coords
#pragma unroll
        for (int u = 0; u < 8; u++) {
            int row = wave * 8 + u;
            sm_d[row * 65 + lane] = bd[u];
            sm_i[row * 65 + lane] = (unsigned short)bi[u];
            if (lane == u) { ssx[row] = Sx[u]; ssy[row] = Sy[u]; ssz[row] = Sz[u]; }
        }
        __syncthreads();     // (A) staging complete
        if (wave == 0) {
            // per-src argmin over 64 lane-slices (ranges ascend -> strict < = first idx)
            const int s = tid;
            float best = sm_d[s * 65];
            int ib = sm_i[s * 65];
            for (int r = 1; r < 64; r++) {
                float dd = sm_d[s * 65 + r];
                int ii = sm_i[s * 65 + r];
                if (dd < best) { best = dd; ib = ii; }
            }
            float4 c = tq[swz32(ib)];
            float X = ssx[s], Y = ssy[s], Z = ssz[s];
            float vals[15] = { X, Y, Z, c.x, c.y, c.z,
                               X * c.x, X * c.y, X * c.z,
                               Y * c.x, Y * c.y, Y * c.z,
                               Z * c.x, Z * c.y, Z * c.z };
#pragma unroll
            for (int k = 0; k < 15; k++) {
                float v = vals[k];
                for (int o = 32; o > 0; o >>= 1) v += __shfl_down(v, o);
                if (lane == 0) st_agent(&partials[((size_t)bufbase + myline) * 16 + k], v);
            }
            if (lane == 0) {
                asm volatile("s_waitcnt vmcnt(0)" ::: "memory");   // moments acked at LLC
                st_agent_i((int*)partials + ((size_t)bufbase + myline) * 16 + 15, iter + 1);
            }
            // per-line poll + immediate fetch (each line gathered as soon as ready)
            double sd[15];
#pragma unroll
            for (int k = 0; k < 15; k++) sd[k] = 0.0;
            if (lane < 32) {
                const float* lp = partials + ((size_t)bufbase + g * 32 + lane) * 16;
                while (ld_agent_i((const int*)lp + 15) < iter + 1) __builtin_amdgcn_s_sleep(1);
                asm volatile("" ::: "memory");
#pragma unroll
                for (int k = 0; k < 15; k++) sd[k] = (double)ld_agent(lp + k);
            }
            // 32-lane double shuffle-tree sum (lanes 32-63 contribute 0)
#pragma unroll
            for (int k = 0; k < 15; k++) {
                for (int o = 16; o > 0; o >>= 1) sd[k] += __shfl_down(sd[k], o);
            }
            if (lane == 0) {
                const double n = (double)NPG_;
                const double rin = 1.0 / (double)NPG_;
                double cs0 = sd[0] * rin, cs1 = sd[1] * rin, cs2 = sd[2] * rin;
                double cc0 = sd[3] * rin, cc1 = sd[4] * rin, cc2 = sd[5] * rin;
                float H[3][3];
                H[0][0] = (float)(sd[6]  - n * cs0 * cc0); H[0][1] = (float)(sd[7]  - n * cs0 * cc1); H[0][2] = (float)(sd[8]  - n * cs0 * cc2);
                H[1][0] = (float)(sd[9]  - n * cs1 * cc0); H[1][1] = (float)(sd[10] - n * cs1 * cc1); H[1][2] = (float)(sd[11] - n * cs1 * cc2);
                H[2][0] = (float)(sd[12] - n * cs2 * cc0); H[2][1] = (float)(sd[13] - n * cs2 * cc1); H[2][2] = (float)(sd[14] - n * cs2 * cc2);
                double R[3][3];
                float fn = 1e-30f;
                for (int i = 0; i < 3; i++) for (int j2 = 0; j2 < 3; j2++) fn += H[i][j2] * H[i][j2];
                float sc = rsqrtf(fn);
                float Xm[3][3];
                for (int i = 0; i < 3; i++) for (int j2 = 0; j2 < 3; j2++) Xm[i][j2] = H[i][j2] * sc;
                float dX = Xm[0][0] * (Xm[1][1]*Xm[2][2] - Xm[1][2]*Xm[2][1])
                         - Xm[0][1] * (Xm[1][0]*Xm[2][2] - Xm[1][2]*Xm[2][0])
                         + Xm[0][2] * (Xm[1][0]*Xm[2][1] - Xm[1][1]*Xm[2][0]);
                if (dX > 1e-4f) {
                    // polar Newton: X <- 0.5*(X + cof(X)/det(X)); R_ref = Q^T
                    for (int itn = 0; itn < 16; ++itn) {
                        float C00 = Xm[1][1]*Xm[2][2] - Xm[1][2]*Xm[2][1];
                        float C01 = Xm[1][2]*Xm[2][0] - Xm[1][0]*Xm[2][2];
                        float C02 = Xm[1][0]*Xm[2][1] - Xm[1][1]*Xm[2][0];
                        float C10 = Xm[2][1]*Xm[0][2] - Xm[2][2]*Xm[0][1];
                        float C11 = Xm[2][2]*Xm[0][0] - Xm[2][0]*Xm[0][2];
                        float C12 = Xm[2][0]*Xm[0][1] - Xm[2][1]*Xm[0][0];
                        float C20 = Xm[0][1]*Xm[1][2] - Xm[0][2]*Xm[1][1];
                        float C21 = Xm[0][2]*Xm[1][0] - Xm[0][0]*Xm[1][2];
                        float C22 = Xm[0][0]*Xm[1][1] - Xm[0][1]*Xm[1][0];
                        float det = Xm[0][0]*C00 + Xm[0][1]*C01 + Xm[0][2]*C02;
                        if (fabsf(det) < 1e-30f) break;
                        float rd = 0.5f / det;
                        Xm[0][0] = 0.5f*Xm[0][0] + C00*rd; Xm[0][1] = 0.5f*Xm[0][1] + C01*rd; Xm[0][2] = 0.5f*Xm[0][2] + C02*rd;
                        Xm[1][0] = 0.5f*Xm[1][0] + C10*rd; Xm[1][1] = 0.5f*Xm[1][1] + C11*rd; Xm[1][2] = 0.5f*Xm[1][2] + C12*rd;
                        Xm[2][0] = 0.5f*Xm[2][0] + C20*rd; Xm[2][1] = 0.5f*Xm[2][1] + C21*rd; Xm[2][2] = 0.5f*Xm[2][2] + C22*rd;
                    }
                    for (int i = 0; i < 3; i++) for (int j2 = 0; j2 < 3; j2++) R[i][j2] = (double)Xm[j2][i];
                } else {
                    // Jacobi-SVD fallback (deterministic)
                    float A[3][3], V[3][3] = {{1,0,0},{0,1,0},{0,0,1}};
                    for (int i = 0; i < 3; i++)
                        for (int j2 = 0; j2 < 3; j2++)
                            A[i][j2] = H[0][i] * H[0][j2] + H[1][i] * H[1][j2] + H[2][i] * H[2][j2];
                    for (int sweep = 0; sweep < 8; ++sweep) {
                        for (int p = 0; p < 2; p++) for (int q = p + 1; q < 3; q++) {
                            float apq = A[p][q];
                            if (fabsf(apq) < 1e-30f) continue;
                            float theta = (A[q][q] - A[p][p]) / (2.f * apq);
                            float t = copysignf(1.f, theta) / (fabsf(theta) + sqrtf(theta * theta + 1.f));
                            float c2 = 1.f / sqrtf(t * t + 1.f);
                            float s2 = t * c2;
                            for (int k = 0; k < 3; k++) { float akp = A[k][p], akq = A[k][q]; A[k][p] = c2*akp - s2*akq; A[k][q] = s2*akp + c2*akq; }
                            for (int k = 0; k < 3; k++) { float apk = A[p][k], aqk = A[q][k]; A[p][k] = c2*apk - s2*aqk; A[q][k] = s2*apk + c2*aqk; }
                            for (int k = 0; k < 3; k++) { float vkp = V[k][p], vkq = V[k][q]; V[k][p] = c2*vkp - s2*vkq; V[k][q] = s2*vkp + c2*vkq; }
                        }
                    }
                    float lam[3] = { A[0][0], A[1][1], A[2][2] };
                    int ord[3] = { 0, 1, 2 };
                    if (lam[ord[1]] > lam[ord[0]]) { int t0 = ord[0]; ord[0] = ord[1]; ord[1] = t0; }
                    if (lam[ord[2]] > lam[ord[0]]) { int t0 = ord[0]; ord[0] = ord[2]; ord[2] = t0; }
                    if (lam[ord[2]] > lam[ord[1]]) { int t0 = ord[1]; ord[1] = ord[2]; ord[2] = t0; }
                    float vc[3][3], uc[3][3];
                    for (int i = 0; i < 3; i++) { vc[i][0] = V[0][ord[i]]; vc[i][1] = V[1][ord[i]]; vc[i][2] = V[2][ord[i]]; }
                    for (int i = 0; i < 3; i++) {
                        float u0 = H[0][0]*vc[i][0] + H[0][1]*vc[i][1] + H[0][2]*vc[i][2];
                        float u1 = H[1][0]*vc[i][0] + H[1][1]*vc[i][1] + H[1][2]*vc[i][2];
                        float u2 = H[2][0]*vc[i][0] + H[2][1]*vc[i][1] + H[2][2]*vc[i][2];
                        for (int j2 = 0; j2 < i; j2++) {
                            float dp = u0*uc[j2][0] + u1*uc[j2][1] + u2*uc[j2][2];
                            u0 -= dp*uc[j2][0]; u1 -= dp*uc[j2][1]; u2 -= dp*uc[j2][2];
                        }
                        float nn2 = sqrtf(u0*u0 + u1*u1 + u2*u2);
                        if (nn2 > 1e-12f) { uc[i][0] = u0/nn2; uc[i][1] = u1/nn2; uc[i][2] = u2/nn2; }
                        else if (i == 2) {
                            uc[2][0] = uc[0][1]*uc[1][2] - uc[0][2]*uc[1][1];
                            uc[2][1] = uc[0][2]*uc[1][0] - uc[0][0]*uc[1][2];
                            uc[2][2] = uc[0][0]*uc[1][1] - uc[0][1]*uc[1][0];
                        } else if (i == 1) {
                            float a0 = (fabsf(uc[0][0]) < 0.9f) ? 1.f : 0.f, a1 = 1.f - a0, a2 = 0.f;
                            float dp = a0*uc[0][0] + a1*uc[0][1] + a2*uc[0][2];
                            a0 -= dp*uc[0][0]; a1 -= dp*uc[0][1]; a2 -= dp*uc[0][2];
                            float nn3 = sqrtf(a0*a0 + a1*a1 + a2*a2);
                            uc[1][0] = a0/nn3; uc[1][1] = a1/nn3; uc[1][2] = a2/nn3;
                        } else { uc[0][0] = 1; uc[0][1] = 0; uc[0][2] = 0; }
                    }
                    float detU = uc[0][0]*(uc[1][1]*uc[2][2] - uc[1][2]*uc[2][1])
                               - uc[0][1]*(uc[1][0]*uc[2][2] - uc[1][2]*uc[2][0])
                               + uc[0][2]*(uc[1][0]*uc[2][1] - uc[1][1]*uc[2][0]);
                    float detV = vc[0][0]*(vc[1][1]*vc[2][2] - vc[1][2]*vc[2][1])
                               - vc[0][1]*(vc[1][0]*vc[2][2] - vc[1][2]*vc[2][0])
                               + vc[0][2]*(vc[1][0]*vc[2][1] - vc[1][1]*vc[2][0]);
                    float sgn = (detU * detV < 0.f) ? -1.f : 1.f;
                    for (int i = 0; i < 3; i++)
                        for (int j2 = 0; j2 < 3; j2++)
                            R[i][j2] = (double)(vc[0][i]*uc[0][j2] + vc[1][i]*uc[1][j2] + sgn * vc[2][i]*uc[2][j2]);
                }
                double tr0 = cc0 - (R[0][0]*cs0 + R[0][1]*cs1 + R[0][2]*cs2);
                double tr1 = cc1 - (R[1][0]*cs0 + R[1][1]*cs1 + R[1][2]*cs2);
                double tr2 = cc2 - (R[2][0]*cs0 + R[2][1]*cs1 + R[2][2]*cs2);
                double An[12];
                for (int i = 0; i < 3; i++)
                    for (int j2 = 0; j2 < 3; j2++)
                        An[i*3+j2] = R[i][0]*Td[0*3+j2] + R[i][1]*Td[1*3+j2] + R[i][2]*Td[2*3+j2];
                An[9]  = R[0][0]*Td[9] + R[0][1]*Td[10] + R[0][2]*Td[11] + tr0;
                An[10] = R[1][0]*Td[9] + R[1][1]*Td[10] + R[1][2]*Td[11] + tr1;
                An[11] = R[2][0]*Td[9] + R[2][1]*Td[10] + R[2][2]*Td[11] + tr2;
#pragma unroll
                for (int k = 0; k < 12; k++) { Td[k] = An[k]; Tsh[k] = (float)An[k]; }
            }
        }
        __syncthreads();     // (B) Tsh ready for all waves
    }

    // ---- chamfer phase: aligned into LDS (final T), both directions, last-block loss ----
    {
        float Tf[12];
#pragma unroll
        for (int k = 0; k < 12; k++) Tf[k] = Tsh[k];
        __syncthreads();   // sm_d/sm_i dead; al aliases scratch
        for (int i = tid; i < NPG_; i += 512) {
            const float* q = &tpos[(size_t)(g * NPG_ + i) * 3];
            float X = Tf[0] * q[0] + Tf[1] * q[1] + Tf[2] * q[2] + Tf[9];
            float Y = Tf[3] * q[0] + Tf[4] * q[1] + Tf[5] * q[2] + Tf[10];
            float Z = Tf[6] * q[0] + Tf[7] * q[1] + Tf[8] * q[2] + Tf[11];
            al[swz32(i)] = make_float4(X, Y, Z, fmaf(X, X, fmaf(Y, Y, Z * Z)));
            if (blk == 0) {
                out_aligned[(size_t)(g * NPG_ + i) * 3 + 0] = X;
                out_aligned[(size_t)(g * NPG_ + i) * 3 + 1] = Y;
                out_aligned[(size_t)(g * NPG_ + i) * 3 + 2] = Z;
            }
        }
        __syncthreads();
        float Ax[8], Ay[8], Az[8], Aw[8], Qx[8], Qy[8], Qz[8], Qw[8], d1[8], d2[8];
#pragma unroll
        for (int u = 0; u < 8; u++) {
            int s = swz32(blk * 64 + wave * 8 + u);
            float4 a4 = al[s]; float4 p4 = tq[s];
            Ax[u] = -2.f * a4.x; Ay[u] = -2.f * a4.y; Az[u] = -2.f * a4.z; Aw[u] = a4.w;
            Qx[u] = -2.f * p4.x; Qy[u] = -2.f * p4.y; Qz[u] = -2.f * p4.z; Qw[u] = p4.w;
            d1[u] = 1e30f; d2[u] = 1e30f;
        }
        const int qbase = lane * 32;
        for (int j = 0; j < 32; j++) {
            int s = qbase + (j ^ (lane & 31));
            float4 t4 = tq[s];
            float4 b4 = al[s];
#pragma unroll
            for (int u = 0; u < 8; u++) {
                d1[u] = fminf(d1[u], fmaf(Ax[u], t4.x, fmaf(Ay[u], t4.y, fmaf(Az[u], t4.z, t4.w))));
                d2[u] = fminf(d2[u], fmaf(Qx[u], b4.x, fmaf(Qy[u], b4.y, fmaf(Qz[u], b4.z, b4.w))));
            }
        }
        float s1 = 0.f, s2 = 0.f;
#pragma unroll
        for (int u = 0; u < 8; u++) {
            float a = d1[u], b = d2[u];
            for (int o = 32; o > 0; o >>= 1) {
                a = fminf(a, __shfl_down(a, o));
                b = fminf(b, __shfl_down(b, o));
            }
            s1 += a + Aw[u];     // + |src|^2 completes the squared distance
            s2 += b + Qw[u];
        }
        if (lane == 0) { wred[wave][0] = s1; wred[wave][1] = s2; }
        __syncthreads();
        if (tid == 0) {
            float t1 = 0.f, t2 = 0.f;
#pragma unroll
            for (int w = 0; w < 8; w++) { t1 += wred[w][0]; t2 += wred[w][1]; }
            st_agent(&chpart[blockIdx.x * 2 + 0], t1);
            st_agent(&chpart[blockIdx.x * 2 + 1], t2);
        }
        __syncthreads();
        if (tid == 0) {
            int old = atomicAdd(&ctrs[128], 1);
            lastFlag = (old == (int)gridDim.x - 1) ? 1 : 0;
        }
        __syncthreads();
        if (!lastFlag) return;
        float v1 = 0.f, v2 = 0.f;
        if (tid < 256) {
            v1 = ld_agent(&chpart[tid * 2 + 0]);
            v2 = ld_agent(&chpart[tid * 2 + 1]);
        }
        for (int o = 32; o > 0; o >>= 1) {
            v1 += __shfl_down(v1, o);
            v2 += __shfl_down(v2, o);
        }
        if (lane == 0 && wave < 4) { wred[wave][0] = v1; wred[wave][1] = v2; }
        __syncthreads();
        if (tid == 0) {
            float tot = 0.f;
#pragma unroll
            for (int w = 0; w < 4; w++) tot += wred[w][0] + wred[w][1];
            out_loss[0] = tot / (float)(NPG_ * B_GRAPHS);
        }
    }
}

// ---------------- launcher ----------------
extern "C" void kernel_launch(void* const* d_in, const int* in_sizes, int n_in,
                              void* d_out, int out_size, void* d_ws, size_t ws_size,
                              hipStream_t stream)
{
    (void)in_sizes; (void)n_in; (void)out_size; (void)ws_size;
    const float* x   = (const float*)d_in[0];
    const int*   ei  = (const int*)d_in[1];
    const float* pos = (const float*)d_in[2];
    const float* W1 = (const float*)d_in[4];
    const float* b1 = (const float*)d_in[5];
    const float* W2 = (const float*)d_in[6];
    const float* b2 = (const float*)d_in[7];
    const float* W3 = (const float*)d_in[8];
    const float* b3 = (const float*)d_in[9];
    const float* Wt = (const float*)d_in[10];
    const float* bt = (const float*)d_in[11];
    const int* row = ei;
    const int* col = ei + E_EDGES;

    char* wsb = (char*)d_ws;
    size_t off_b = 0;
    auto alloc = [&](size_t bytes) -> void* {
        void* p = wsb + off_b;
        off_b = (off_b + bytes + 255) & ~(size_t)255;
        return p;
    };
    // contiguous zero region: counts (64KB) + partials (32KB) + ctrs (1KB)
    int*    counts   = (int*)alloc((size_t)N_NODES * 4);
    float*  partials = (float*)alloc((size_t)2 * 256 * 16 * 4);
    int*    ctrs     = (int*)alloc((size_t)256 * 4);
    int*    offs     = (int*)alloc((size_t)(N_NODES + 1) * 4);
    int*    cursor   = (int*)alloc((size_t)N_NODES * 4);
    int*    srcid    = (int*)alloc((size_t)E_EDGES * 4);
    float*  normv    = (float*)alloc((size_t)E_EDGES * 4);
    float*  dinv     = (float*)alloc((size_t)N_NODES * 4);
    unsigned short* xb  = (unsigned short*)alloc((size_t)N_NODES * F_IN * 2);
    unsigned short* W1b = (unsigned short*)alloc((size_t)F_IN * F_HID * 2);
    unsigned short* W2b = (unsigned short*)alloc((size_t)F_HID * F_HID * 2);
    unsigned short* W3b = (unsigned short*)alloc((size_t)F_HID * F_OUT * 2);
    unsigned short* bufA = (unsigned short*)alloc((size_t)N_NODES * F_HID * 2);
    unsigned short* bufB = (unsigned short*)alloc((size_t)N_NODES * F_HID * 2);
    unsigned short* bufC = (unsigned short*)alloc((size_t)N_NODES * F_HID * 2);
    float*  tpos     = (float*)alloc((size_t)N_NODES * 3 * 4);
    float*  chpart   = (float*)alloc((size_t)256 * 2 * 4);

    float* out_h       = (float*)d_out;
    float* out_aligned = out_h + (size_t)N_NODES * F_OUT;
    float* out_loss    = out_aligned + (size_t)N_NODES * 3;

    // 1: zero counts + partials(tags) + ctrs in ONE stream-ordered memset (replay-safe)
    hipMemsetAsync(counts, 0, (size_t)N_NODES * 4 + 2 * 256 * 16 * 4 + 256 * 4, stream);
    // 2: converts + edge count
    k_prep<<<3584, 256, 0, stream>>>(x, xb, W1, W2, W3, W1b, W2b, W3b, col, counts);
    // 3-4: CSR
    k_scan<<<1, 1024, 0, stream>>>(counts, offs, cursor, dinv);
    k_scatter<<<E_EDGES / 256, 256, 0, stream>>>(row, col, cursor, dinv, srcid, normv);

    // 5: layer1 aggregate (x bf16 -> bufA)
    k_agg128<0, 0><<<N_NODES / 2, 128, 0, stream>>>(xb, bufA, offs, srcid, normv, dinv,
            nullptr, 0, nullptr, nullptr, nullptr, nullptr);
    // 6: gemm1 + bias + relu
    {
        dim3 grid(F_HID / 64, N_NODES / 128);
        k_gemm_bf16<<<grid, 256, 0, stream>>>(bufA, W1b, b1, bufB, N_NODES, F_HID, F_IN, 1);
    }
    // 7: gemm2 (no bias)
    {
        dim3 grid(F_HID / 64, N_NODES / 128);
        k_gemm_bf16<<<grid, 256, 0, stream>>>(bufB, W2b, nullptr, bufC, N_NODES, F_HID, F_HID, 0);
    }
    // 8: layer2 aggregate + b2 + relu (one wave per node, uint2)
    k_agg256<<<N_NODES / 2, 128, 0, stream>>>(bufC, bufA, offs, srcid, normv, dinv, b2, 1);
    // 9: gemm3
    {
        dim3 grid(F_OUT / 64, N_NODES / 128);
        k_gemm_bf16<<<grid, 256, 0, stream>>>(bufA, W3b, nullptr, bufB, N_NODES, F_OUT, F_HID, 0);
    }
    // 10: layer3 aggregate + b3 -> out_h (fp32), fused tpos
    k_agg128<1, 1><<<N_NODES / 2, 128, 0, stream>>>(bufB, out_h, offs, srcid, normv, dinv,
            b3, 0, Wt, bt, pos, tpos);

    // 11: persistent ICP (10 iterations) + apply + chamfer + loss (256 blocks, 1/CU)
    k_icp_all<<<256, 512, 0, stream>>>(tpos, pos, partials, chpart, ctrs,
            out_aligned, out_loss);
}

// Round 12
// 299.354 us; speedup vs baseline: 1.0768x; 1.0768x over previous
//
#include <hip/hip_runtime.h>
#include <math.h>

#define N_NODES 16384
#define B_GRAPHS 8
#define NPG_     2048
#define E_EDGES  262144
#define F_IN  128
#define F_HID 256
#define F_OUT 128
#define ICP_IT 10

typedef __attribute__((ext_vector_type(8))) short bf16x8;
typedef __attribute__((ext_vector_type(4))) float f32x4;

__device__ __forceinline__ float b2f(unsigned short u) {
    union { unsigned int u; float f; } v; v.u = ((unsigned int)u) << 16; return v.f;
}
__device__ __forceinline__ unsigned short f2b(float f) {
    union { float f; unsigned int u; } v; v.f = f;
    unsigned int r = v.u + 0x7FFFu + ((v.u >> 16) & 1u);
    return (unsigned short)(r >> 16);
}
// XOR swizzle within 32-element groups: spreads lane-sliced LDS scans over banks.
__device__ __forceinline__ int swz32(int i) {
    return (i & ~31) | ((i & 31) ^ ((i >> 5) & 31));
}
// Agent-scope accesses (used ONLY in chamfer last-block loss; validated R4-R10).
__device__ __forceinline__ void st_agent(float* p, float v) {
    __hip_atomic_store(p, v, __ATOMIC_RELAXED, __HIP_MEMORY_SCOPE_AGENT);
}
__device__ __forceinline__ float ld_agent(const float* p) {
    return __hip_atomic_load(p, __ATOMIC_RELAXED, __HIP_MEMORY_SCOPE_AGENT);
}

// ---- Kabsch: moments -> incremental R,t -> compose with Tp (lane-local, fp64 I/O) -------
__device__ void kabsch_update(const double sd[15], const double Tp[12], double Tn[12])
{
    const double n = (double)NPG_;
    const double rin = 1.0 / n;
    double cs0 = sd[0]*rin, cs1 = sd[1]*rin, cs2 = sd[2]*rin;
    double cc0 = sd[3]*rin, cc1 = sd[4]*rin, cc2 = sd[5]*rin;
    float H[3][3];
    H[0][0] = (float)(sd[6]  - n*cs0*cc0); H[0][1] = (float)(sd[7]  - n*cs0*cc1); H[0][2] = (float)(sd[8]  - n*cs0*cc2);
    H[1][0] = (float)(sd[9]  - n*cs1*cc0); H[1][1] = (float)(sd[10] - n*cs1*cc1); H[1][2] = (float)(sd[11] - n*cs1*cc2);
    H[2][0] = (float)(sd[12] - n*cs2*cc0); H[2][1] = (float)(sd[13] - n*cs2*cc1); H[2][2] = (float)(sd[14] - n*cs2*cc2);
    double R[3][3];
    float fn = 1e-30f;
    for (int i = 0; i < 3; i++) for (int j = 0; j < 3; j++) fn += H[i][j] * H[i][j];
    float sc = rsqrtf(fn);
    float Xm[3][3];
    for (int i = 0; i < 3; i++) for (int j = 0; j < 3; j++) Xm[i][j] = H[i][j] * sc;
    float dX = Xm[0][0]*(Xm[1][1]*Xm[2][2]-Xm[1][2]*Xm[2][1])
             - Xm[0][1]*(Xm[1][0]*Xm[2][2]-Xm[1][2]*Xm[2][0])
             + Xm[0][2]*(Xm[1][0]*Xm[2][1]-Xm[1][1]*Xm[2][0]);
    if (dX > 1e-4f) {
        // polar Newton: X <- 0.5*(X + cof(X)/det(X)); R_ref = Q^T
        for (int itn = 0; itn < 16; ++itn) {
            float C00 = Xm[1][1]*Xm[2][2]-Xm[1][2]*Xm[2][1];
            float C01 = Xm[1][2]*Xm[2][0]-Xm[1][0]*Xm[2][2];
            float C02 = Xm[1][0]*Xm[2][1]-Xm[1][1]*Xm[2][0];
            float C10 = Xm[2][1]*Xm[0][2]-Xm[2][2]*Xm[0][1];
            float C11 = Xm[2][2]*Xm[0][0]-Xm[2][0]*Xm[0][2];
            float C12 = Xm[2][0]*Xm[0][1]-Xm[2][1]*Xm[0][0];
            float C20 = Xm[0][1]*Xm[1][2]-Xm[0][2]*Xm[1][1];
            float C21 = Xm[0][2]*Xm[1][0]-Xm[0][0]*Xm[1][2];
            float C22 = Xm[0][0]*Xm[1][1]-Xm[0][1]*Xm[1][0];
            float det = Xm[0][0]*C00 + Xm[0][1]*C01 + Xm[0][2]*C02;
            if (fabsf(det) < 1e-30f) break;
            float rd = 0.5f / det;
            Xm[0][0]=0.5f*Xm[0][0]+C00*rd; Xm[0][1]=0.5f*Xm[0][1]+C01*rd; Xm[0][2]=0.5f*Xm[0][2]+C02*rd;
            Xm[1][0]=0.5f*Xm[1][0]+C10*rd; Xm[1][1]=0.5f*Xm[1][1]+C11*rd; Xm[1][2]=0.5f*Xm[1][2]+C12*rd;
            Xm[2][0]=0.5f*Xm[2][0]+C20*rd; Xm[2][1]=0.5f*Xm[2][1]+C21*rd; Xm[2][2]=0.5f*Xm[2][2]+C22*rd;
        }
        for (int i = 0; i < 3; i++) for (int j = 0; j < 3; j++) R[i][j] = (double)Xm[j][i];
    } else {
        // Jacobi-SVD fallback (deterministic)
        float A[3][3], V[3][3] = {{1,0,0},{0,1,0},{0,0,1}};
        for (int i = 0; i < 3; i++)
            for (int j = 0; j < 3; j++)
                A[i][j] = H[0][i]*H[0][j] + H[1][i]*H[1][j] + H[2][i]*H[2][j];
        for (int sweep = 0; sweep < 8; ++sweep) {
            for (int p = 0; p < 2; p++) for (int q = p + 1; q < 3; q++) {
                float apq = A[p][q];
                if (fabsf(apq) < 1e-30f) continue;
                float theta = (A[q][q] - A[p][p]) / (2.f * apq);
                float t = copysignf(1.f, theta) / (fabsf(theta) + sqrtf(theta*theta + 1.f));
                float c = 1.f / sqrtf(t*t + 1.f);
                float s = t * c;
                for (int k = 0; k < 3; k++) { float akp=A[k][p], akq=A[k][q]; A[k][p]=c*akp-s*akq; A[k][q]=s*akp+c*akq; }
                for (int k = 0; k < 3; k++) { float apk=A[p][k], aqk=A[q][k]; A[p][k]=c*apk-s*aqk; A[q][k]=s*apk+c*aqk; }
                for (int k = 0; k < 3; k++) { float vkp=V[k][p], vkq=V[k][q]; V[k][p]=c*vkp-s*vkq; V[k][q]=s*vkp+c*vkq; }
            }
        }
        float lam[3] = { A[0][0], A[1][1], A[2][2] };
        int ord[3] = { 0, 1, 2 };
        if (lam[ord[1]] > lam[ord[0]]) { int t0=ord[0]; ord[0]=ord[1]; ord[1]=t0; }
        if (lam[ord[2]] > lam[ord[0]]) { int t0=ord[0]; ord[0]=ord[2]; ord[2]=t0; }
        if (lam[ord[2]] > lam[ord[1]]) { int t0=ord[1]; ord[1]=ord[2]; ord[2]=t0; }
        float vc[3][3], uc[3][3];
        for (int i = 0; i < 3; i++) { vc[i][0]=V[0][ord[i]]; vc[i][1]=V[1][ord[i]]; vc[i][2]=V[2][ord[i]]; }
        for (int i = 0; i < 3; i++) {
            float u0 = H[0][0]*vc[i][0] + H[0][1]*vc[i][1] + H[0][2]*vc[i][2];
            float u1 = H[1][0]*vc[i][0] + H[1][1]*vc[i][1] + H[1][2]*vc[i][2];
            float u2 = H[2][0]*vc[i][0] + H[2][1]*vc[i][1] + H[2][2]*vc[i][2];
            for (int j = 0; j < i; j++) {
                float dp = u0*uc[j][0] + u1*uc[j][1] + u2*uc[j][2];
                u0 -= dp*uc[j][0]; u1 -= dp*uc[j][1]; u2 -= dp*uc[j][2];
            }
            float nn2 = sqrtf(u0*u0 + u1*u1 + u2*u2);
            if (nn2 > 1e-12f) { uc[i][0]=u0/nn2; uc[i][1]=u1/nn2; uc[i][2]=u2/nn2; }
            else if (i == 2) {
                uc[2][0]=uc[0][1]*uc[1][2]-uc[0][2]*uc[1][1];
                uc[2][1]=uc[0][2]*uc[1][0]-uc[0][0]*uc[1][2];
                uc[2][2]=uc[0][0]*uc[1][1]-uc[0][1]*uc[1][0];
            } else if (i == 1) {
                float a0 = (fabsf(uc[0][0]) < 0.9f) ? 1.f : 0.f, a1 = 1.f - a0, a2 = 0.f;
                float dp = a0*uc[0][0] + a1*uc[0][1] + a2*uc[0][2];
                a0 -= dp*uc[0][0]; a1 -= dp*uc[0][1]; a2 -= dp*uc[0][2];
                float nn3 = sqrtf(a0*a0 + a1*a1 + a2*a2);
                uc[1][0]=a0/nn3; uc[1][1]=a1/nn3; uc[1][2]=a2/nn3;
            } else { uc[0][0]=1; uc[0][1]=0; uc[0][2]=0; }
        }
        float detU = uc[0][0]*(uc[1][1]*uc[2][2]-uc[1][2]*uc[2][1])
                   - uc[0][1]*(uc[1][0]*uc[2][2]-uc[1][2]*uc[2][0])
                   + uc[0][2]*(uc[1][0]*uc[2][1]-uc[1][1]*uc[2][0]);
        float detV = vc[0][0]*(vc[1][1]*vc[2][2]-vc[1][2]*vc[2][1])
                   - vc[0][1]*(vc[1][0]*vc[2][2]-vc[1][2]*vc[2][0])
                   + vc[0][2]*(vc[1][0]*vc[2][1]-vc[1][1]*vc[2][0]);
        float sgn = (detU * detV < 0.f) ? -1.f : 1.f;
        for (int i = 0; i < 3; i++)
            for (int j = 0; j < 3; j++)
                R[i][j] = (double)(vc[0][i]*uc[0][j] + vc[1][i]*uc[1][j] + sgn*vc[2][i]*uc[2][j]);
    }
    double tr0 = cc0 - (R[0][0]*cs0 + R[0][1]*cs1 + R[0][2]*cs2);
    double tr1 = cc1 - (R[1][0]*cs0 + R[1][1]*cs1 + R[1][2]*cs2);
    double tr2 = cc2 - (R[2][0]*cs0 + R[2][1]*cs1 + R[2][2]*cs2);
    for (int i = 0; i < 3; i++)
        for (int j = 0; j < 3; j++)
            Tn[i*3+j] = R[i][0]*Tp[0*3+j] + R[i][1]*Tp[1*3+j] + R[i][2]*Tp[2*3+j];
    Tn[9]  = R[0][0]*Tp[9] + R[0][1]*Tp[10] + R[0][2]*Tp[11] + tr0;
    Tn[10] = R[1][0]*Tp[9] + R[1][1]*Tp[10] + R[1][2]*Tp[11] + tr1;
    Tn[11] = R[2][0]*Tp[9] + R[2][1]*Tp[10] + R[2][2]*Tp[11] + tr2;
}

// Wave-0 helper: gather 32x15 partials (plain cached), tree-sum, compute Tsh (+opt TdOut).
__device__ void compute_T_wave0(int lane, int g, int iter,
        const float* __restrict__ Pin, const double* __restrict__ TdIn,
        double* __restrict__ TdOut, float* Tsh, int writeTd, int isBlock0)
{
    if (iter == 0) {
        if (lane < 12) Tsh[lane] = (lane == 0 || lane == 4 || lane == 8) ? 1.f : 0.f;
        return;
    }
    double sd[15];
#pragma unroll
    for (int k = 0; k < 15; k++) sd[k] = 0.0;
    if (lane < 32) {
        const float* lp = Pin + ((size_t)g * 32 + lane) * 16;
#pragma unroll
        for (int k = 0; k < 15; k++) sd[k] = (double)lp[k];
    }
#pragma unroll
    for (int k = 0; k < 15; k++)
        for (int o = 16; o > 0; o >>= 1) sd[k] += __shfl_down(sd[k], o);
    if (lane == 0) {
        double Tp[12], Tn[12];
        if (iter == 1) {
#pragma unroll
            for (int k = 0; k < 12; k++) Tp[k] = (k == 0 || k == 4 || k == 8) ? 1.0 : 0.0;
        } else {
#pragma unroll
            for (int k = 0; k < 12; k++) Tp[k] = TdIn[k];
        }
        kabsch_update(sd, Tp, Tn);
#pragma unroll
        for (int k = 0; k < 12; k++) Tsh[k] = (float)Tn[k];
        if (writeTd && isBlock0) {
#pragma unroll
            for (int k = 0; k < 12; k++) TdOut[k] = Tn[k];
        }
    }
}

// ------- k_prep: x->bf16, pos4 precompute, weight transposes, edge count ------------------
__global__ __launch_bounds__(256) void k_prep(
    const float* __restrict__ x, unsigned short* __restrict__ xb,
    const float* __restrict__ pos, float4* __restrict__ pos4,
    const float* __restrict__ W1, const float* __restrict__ W2, const float* __restrict__ W3,
    unsigned short* __restrict__ W1b, unsigned short* __restrict__ W2b, unsigned short* __restrict__ W3b,
    const int* __restrict__ col, int* __restrict__ counts)
{
    const int b = blockIdx.x, tid = threadIdx.x;
    if (b < 2048) {                       // x: 524288 float4 -> uint2
        int i = b * 256 + tid;
        float4 v = ((const float4*)x)[i];
        uint2 o;
        o.x = (unsigned int)f2b(v.x) | ((unsigned int)f2b(v.y) << 16);
        o.y = (unsigned int)f2b(v.z) | ((unsigned int)f2b(v.w) << 16);
        ((uint2*)xb)[i] = o;
    } else if (b < 2112) {                // pos4 = (x,y,z,|p|^2)
        int i = (b - 2048) * 256 + tid;
        float px = pos[i*3], py = pos[i*3+1], pz = pos[i*3+2];
        pos4[i] = make_float4(px, py, pz, fmaf(px, px, fmaf(py, py, pz * pz)));
    } else if (b < 2240) {                // W1 [128][256] -> W1b [256][128]
        int idx = (b - 2112) * 256 + tid;
        int k = idx >> 8, n = idx & 255;
        W1b[n * 128 + k] = f2b(W1[idx]);
    } else if (b < 2496) {                // W2 [256][256] -> W2b [256][256]
        int idx = (b - 2240) * 256 + tid;
        int k = idx >> 8, n = idx & 255;
        W2b[n * 256 + k] = f2b(W2[idx]);
    } else if (b < 2624) {                // W3 [256][128] -> W3b [128][256]
        int idx = (b - 2496) * 256 + tid;
        int k = idx >> 7, n = idx & 127;
        W3b[n * 256 + k] = f2b(W3[idx]);
    } else {                              // edge in-degree count
        int e = (b - 2624) * 256 + tid;
        atomicAdd(&counts[col[e]], 1);
    }
}

// ---------------- CSR build ----------------
__global__ __launch_bounds__(1024) void k_scan(const int* __restrict__ counts,
        int* __restrict__ offs, int* __restrict__ cursor, float* __restrict__ dinv)
{
    __shared__ int wtot[16];
    const int t = threadIdx.x;
    const int base = t * 16;
    int local[16];
    int s = 0;
#pragma unroll
    for (int i = 0; i < 16; i++) { local[i] = counts[base + i]; s += local[i]; }
    const int lane = t & 63, w = t >> 6;
    int inc = s;
    for (int o = 1; o < 64; o <<= 1) {
        int v = __shfl_up(inc, o);
        if (lane >= o) inc += v;
    }
    if (lane == 63) wtot[w] = inc;
    __syncthreads();
    if (t < 16) {
        int v = wtot[t];
        for (int o = 1; o < 16; o <<= 1) {
            int u = __shfl_up(v, o);
            if (t >= o) v += u;
        }
        wtot[t] = v;
    }
    __syncthreads();
    int run = (w > 0 ? wtot[w - 1] : 0) + (inc - s);
#pragma unroll
    for (int i = 0; i < 16; i++) {
        offs[base + i]   = run;
        cursor[base + i] = run;
        dinv[base + i]   = rsqrtf((float)(local[i] + 1));  // deg = indeg + self loop
        run += local[i];
    }
    if (t == 1023) offs[N_NODES] = run;
}

__global__ void k_scatter(const int* __restrict__ row, const int* __restrict__ col,
        int* __restrict__ cursor, const float* __restrict__ dinv,
        int* __restrict__ srcid, float* __restrict__ normv)
{
    int e = blockIdx.x * 256 + threadIdx.x;
    if (e >= E_EDGES) return;
    int r = row[e], c = col[e];
    int p = atomicAdd(&cursor[c], 1);
    srcid[p] = r;
    normv[p] = dinv[r] * dinv[c];
}

// ---------------- GCN aggregation W=128 (bf16 in, fp32 acc); unroll-4; fused tpos ---------
template<int OUTF, int FUSET>
__global__ __launch_bounds__(128) void k_agg128(const unsigned short* __restrict__ X,
        void* __restrict__ Y,
        const int* __restrict__ offs, const int* __restrict__ srcid,
        const float* __restrict__ normv, const float* __restrict__ dinv,
        const float* __restrict__ bias, int relu,
        const float* __restrict__ Wt, const float* __restrict__ bt,
        const float* __restrict__ pos, float* __restrict__ tposO)
{
    const int local = threadIdx.x >> 6;
    const int n = blockIdx.x * 2 + local;
    const int j = threadIdx.x & 63;
    const unsigned int* Xu = (const unsigned int*)X;
    float di = dinv[n];
    float w0 = di * di;
    unsigned int v = Xu[(size_t)n * 64 + j];
    float a0 = b2f((unsigned short)v) * w0;
    float a1 = b2f((unsigned short)(v >> 16)) * w0;
    int p = offs[n];
    const int p1 = offs[n + 1];
    for (; p + 3 < p1; p += 4) {
        int s0i = srcid[p], s1i = srcid[p + 1], s2i = srcid[p + 2], s3i = srcid[p + 3];
        float n0 = normv[p], n1 = normv[p + 1], n2 = normv[p + 2], n3 = normv[p + 3];
        unsigned int v0 = Xu[(size_t)s0i * 64 + j];
        unsigned int v1 = Xu[(size_t)s1i * 64 + j];
        unsigned int v2 = Xu[(size_t)s2i * 64 + j];
        unsigned int v3 = Xu[(size_t)s3i * 64 + j];
        a0 = fmaf(b2f((unsigned short)v0), n0, a0);
        a1 = fmaf(b2f((unsigned short)(v0 >> 16)), n0, a1);
        a0 = fmaf(b2f((unsigned short)v1), n1, a0);
        a1 = fmaf(b2f((unsigned short)(v1 >> 16)), n1, a1);
        a0 = fmaf(b2f((unsigned short)v2), n2, a0);
        a1 = fmaf(b2f((unsigned short)(v2 >> 16)), n2, a1);
        a0 = fmaf(b2f((unsigned short)v3), n3, a0);
        a1 = fmaf(b2f((unsigned short)(v3 >> 16)), n3, a1);
    }
    for (; p < p1; ++p) {
        unsigned int va = Xu[(size_t)srcid[p] * 64 + j]; float na = normv[p];
        a0 = fmaf(b2f((unsigned short)va), na, a0);
        a1 = fmaf(b2f((unsigned short)(va >> 16)), na, a1);
    }
    if (bias) { a0 += bias[2 * j]; a1 += bias[2 * j + 1]; }
    if (relu) { a0 = fmaxf(a0, 0.f); a1 = fmaxf(a1, 0.f); }
    if (OUTF) {
        float* Yf = (float*)Y;
        Yf[(size_t)n * 128 + 2 * j]     = a0;
        Yf[(size_t)n * 128 + 2 * j + 1] = a1;
    } else {
        ((unsigned int*)Y)[(size_t)n * 64 + j] =
            (unsigned int)f2b(a0) | ((unsigned int)f2b(a1) << 16);
    }
    if (FUSET) {
        float wt0 = Wt[6 * j + 0], wt1 = Wt[6 * j + 1], wt2 = Wt[6 * j + 2];
        float wt3 = Wt[6 * j + 3], wt4 = Wt[6 * j + 4], wt5 = Wt[6 * j + 5];
        float s0 = a0 * wt0 + a1 * wt3;
        float s1 = a0 * wt1 + a1 * wt4;
        float s2 = a0 * wt2 + a1 * wt5;
        for (int o = 32; o > 0; o >>= 1) {
            s0 += __shfl_down(s0, o);
            s1 += __shfl_down(s1, o);
            s2 += __shfl_down(s2, o);
        }
        if (j == 0) {
            tposO[n * 3 + 0] = pos[n * 3 + 0] + s0 + bt[0];
            tposO[n * 3 + 1] = pos[n * 3 + 1] + s1 + bt[1];
            tposO[n * 3 + 2] = pos[n * 3 + 2] + s2 + bt[2];
        }
    }
}

// ---------------- GCN aggregation W=256: one wave per node, uint2 (4 cols/lane) -----------
__global__ __launch_bounds__(128) void k_agg256(const unsigned short* __restrict__ X,
        unsigned short* __restrict__ Y,
        const int* __restrict__ offs, const int* __restrict__ srcid,
        const float* __restrict__ normv, const float* __restrict__ dinv,
        const float* __restrict__ bias, int relu)
{
    const int local = threadIdx.x >> 6;
    const int n = blockIdx.x * 2 + local;
    const int lane = threadIdx.x & 63;
    const uint2* Xu = (const uint2*)X;
    float di = dinv[n];
    float w0 = di * di;
    uint2 v = Xu[(size_t)n * 64 + lane];
    float a0 = b2f((unsigned short)v.x) * w0;
    float a1 = b2f((unsigned short)(v.x >> 16)) * w0;
    float a2 = b2f((unsigned short)v.y) * w0;
    float a3 = b2f((unsigned short)(v.y >> 16)) * w0;
    int p = offs[n];
    const int p1 = offs[n + 1];
    for (; p + 3 < p1; p += 4) {
        int s0i = srcid[p], s1i = srcid[p + 1], s2i = srcid[p + 2], s3i = srcid[p + 3];
        float n0 = normv[p], n1 = normv[p + 1], n2 = normv[p + 2], n3 = normv[p + 3];
        uint2 v0 = Xu[(size_t)s0i * 64 + lane];
        uint2 v1 = Xu[(size_t)s1i * 64 + lane];
        uint2 v2 = Xu[(size_t)s2i * 64 + lane];
        uint2 v3 = Xu[(size_t)s3i * 64 + lane];
        a0 = fmaf(b2f((unsigned short)v0.x), n0, a0);
        a1 = fmaf(b2f((unsigned short)(v0.x >> 16)), n0, a1);
        a2 = fmaf(b2f((unsigned short)v0.y), n0, a2);
        a3 = fmaf(b2f((unsigned short)(v0.y >> 16)), n0, a3);
        a0 = fmaf(b2f((unsigned short)v1.x), n1, a0);
        a1 = fmaf(b2f((unsigned short)(v1.x >> 16)), n1, a1);
        a2 = fmaf(b2f((unsigned short)v1.y), n1, a2);
        a3 = fmaf(b2f((unsigned short)(v1.y >> 16)), n1, a3);
        a0 = fmaf(b2f((unsigned short)v2.x), n2, a0);
        a1 = fmaf(b2f((unsigned short)(v2.x >> 16)), n2, a1);
        a2 = fmaf(b2f((unsigned short)v2.y), n2, a2);
        a3 = fmaf(b2f((unsigned short)(v2.y >> 16)), n2, a3);
        a0 = fmaf(b2f((unsigned short)v3.x), n3, a0);
        a1 = fmaf(b2f((unsigned short)(v3.x >> 16)), n3, a1);
        a2 = fmaf(b2f((unsigned short)v3.y), n3, a2);
        a3 = fmaf(b2f((unsigned short)(v3.y >> 16)), n3, a3);
    }
    for (; p < p1; ++p) {
        uint2 va = Xu[(size_t)srcid[p] * 64 + lane]; float na = normv[p];
        a0 = fmaf(b2f((unsigned short)va.x), na, a0);
        a1 = fmaf(b2f((unsigned short)(va.x >> 16)), na, a1);
        a2 = fmaf(b2f((unsigned short)va.y), na, a2);
        a3 = fmaf(b2f((unsigned short)(va.y >> 16)), na, a3);
    }
    if (bias) {
        float4 bv = ((const float4*)bias)[lane];
        a0 += bv.x; a1 += bv.y; a2 += bv.z; a3 += bv.w;
    }
    if (relu) {
        a0 = fmaxf(a0, 0.f); a1 = fmaxf(a1, 0.f);
        a2 = fmaxf(a2, 0.f); a3 = fmaxf(a3, 0.f);
    }
    uint2 o;
    o.x = (unsigned int)f2b(a0) | ((unsigned int)f2b(a1) << 16);
    o.y = (unsigned int)f2b(a2) | ((unsigned int)f2b(a3) << 16);
    ((uint2*)Y)[(size_t)n * 64 + lane] = o;
}

// ---------------- bf16 MFMA GEMM: C[M,N] = A[M,K] @ Bt[N,K]^T (+bias,relu) ----------------
__global__ __launch_bounds__(256) void k_gemm_bf16(
    const unsigned short* __restrict__ A,   // [M][K] bf16
    const unsigned short* __restrict__ Bt,  // [N][K] bf16
    const float* __restrict__ bias, unsigned short* __restrict__ C,
    int M, int N, int K, int relu)
{
    __shared__ __align__(16) unsigned short As[128 * 64];
    __shared__ __align__(16) unsigned short Bs[64 * 64];
    const int tid  = threadIdx.x;
    const int lane = tid & 63;
    const int wave = tid >> 6;
    const int bm = blockIdx.y * 128, bn = blockIdx.x * 64;
    const int wm = (wave >> 1) * 64, wn = (wave & 1) * 32;
    f32x4 acc[4][2];
#pragma unroll
    for (int mf = 0; mf < 4; mf++)
#pragma unroll
        for (int nf = 0; nf < 2; nf++) acc[mf][nf] = (f32x4){0.f, 0.f, 0.f, 0.f};

    for (int k0 = 0; k0 < K; k0 += 64) {
#pragma unroll
        for (int i = 0; i < 4; i++) {
            int idx = i * 256 + tid;
            int m = idx >> 3, slot = idx & 7;
            const unsigned short* src = A + (size_t)(bm + m) * K + k0 + ((slot ^ (m & 7)) << 3);
            __builtin_amdgcn_global_load_lds(
                (const __attribute__((address_space(1))) unsigned int*)src,
                (__attribute__((address_space(3))) unsigned int*)(As + (size_t)i * 2048 + wave * 512),
                16, 0, 0);
        }
#pragma unroll
        for (int i = 0; i < 2; i++) {
            int idx = i * 256 + tid;
            int n = idx >> 3, slot = idx & 7;
            const unsigned short* src = Bt + (size_t)(bn + n) * K + k0 + ((slot ^ (n & 7)) << 3);
            __builtin_amdgcn_global_load_lds(
                (const __attribute__((address_space(1))) unsigned int*)src,
                (__attribute__((address_space(3))) unsigned int*)(Bs + (size_t)i * 2048 + wave * 512),
                16, 0, 0);
        }
        __syncthreads();
        bf16x8 af[4][2], bfr[2][2];
        const int qd = lane >> 4;
#pragma unroll
        for (int s = 0; s < 2; s++) {
#pragma unroll
            for (int mf = 0; mf < 4; mf++) {
                int m = wm + mf * 16 + (lane & 15);
                int slot = (s * 4 + qd) ^ (m & 7);
                af[mf][s] = *(const bf16x8*)(As + m * 64 + slot * 8);
            }
#pragma unroll
            for (int nf = 0; nf < 2; nf++) {
                int n = wn + nf * 16 + (lane & 15);
                int slot = (s * 4 + qd) ^ (n & 7);
                bfr[nf][s] = *(const bf16x8*)(Bs + n * 64 + slot * 8);
            }
        }
#pragma unroll
        for (int s = 0; s < 2; s++)
#pragma unroll
            for (int mf = 0; mf < 4; mf++)
#pragma unroll
                for (int nf = 0; nf < 2; nf++)
                    acc[mf][nf] = __builtin_amdgcn_mfma_f32_16x16x32_bf16(
                        af[mf][s], bfr[nf][s], acc[mf][nf], 0, 0, 0);
        __syncthreads();
    }
#pragma unroll
    for (int nf = 0; nf < 2; nf++) {
        int col = bn + wn + nf * 16 + (lane & 15);
        float bv = bias ? bias[col] : 0.f;
#pragma unroll
        for (int mf = 0; mf < 4; mf++) {
#pragma unroll
            for (int r = 0; r < 4; r++) {
                int row = bm + wm + mf * 16 + (lane >> 4) * 4 + r;
                float v = acc[mf][nf][r] + bv;
                if (relu) v = fmaxf(v, 0.f);
                C[(size_t)row * N + col] = f2b(v);
            }
        }
    }
}

// ---------------- ICP NN iteration (ONE launch per iteration; kernel boundary = sync) -----
// Wave 0 recomputes T(iter) from the previous launch's partials (plain cached loads, no
// spin, no agent ops) while the other waves stage targets; block 0 persists T as doubles.
__global__ __launch_bounds__(512) void k_icp_nn(
    const float4* __restrict__ pos4, const float* __restrict__ tpos,
    const float* __restrict__ Pin, float* __restrict__ Pout,     // [256][16] each
    const double* __restrict__ TdIn, double* __restrict__ TdOut, // [8][12] slices
    int iter)
{
    const int g = blockIdx.x >> 5, blk = blockIdx.x & 31;
    const int tid = threadIdx.x;
    const int wave = tid >> 6, lane = tid & 63;
    __shared__ float4 tq[NPG_];                                  // 32KB swizzled, w=|t|^2
    __shared__ float sm_d[64 * 65];
    __shared__ unsigned short sm_i[64 * 65];
    __shared__ float ssx[64], ssy[64], ssz[64];
    __shared__ float Tsh[12];

    for (int i = tid; i < NPG_; i += 512)
        tq[swz32(i)] = pos4[(size_t)g * NPG_ + i];
    // own 64 source points
    float Px[8], Py[8], Pz[8];
#pragma unroll
    for (int u = 0; u < 8; u++) {
        int n = g * NPG_ + blk * 64 + wave * 8 + u;
        Px[u] = tpos[n * 3 + 0]; Py[u] = tpos[n * 3 + 1]; Pz[u] = tpos[n * 3 + 2];
    }
    if (wave == 0)
        compute_T_wave0(lane, g, iter, Pin, TdIn + g * 12, TdOut + g * 12, Tsh,
                        iter > 0, blk == 0);
    __syncthreads();

    float Tf[12];
#pragma unroll
    for (int k = 0; k < 12; k++) Tf[k] = Tsh[k];
    float Sx[8], Sy[8], Sz[8], Tx[8], Ty[8], Tz[8], bd[8];
    int bi[8];
#pragma unroll
    for (int u = 0; u < 8; u++) {
        float X = Tf[0] * Px[u] + Tf[1] * Py[u] + Tf[2] * Pz[u] + Tf[9];
        float Y = Tf[3] * Px[u] + Tf[4] * Py[u] + Tf[5] * Pz[u] + Tf[10];
        float Z = Tf[6] * Px[u] + Tf[7] * Py[u] + Tf[8] * Pz[u] + Tf[11];
        Sx[u] = X; Sy[u] = Y; Sz[u] = Z;
        Tx[u] = -2.f * X; Ty[u] = -2.f * Y; Tz[u] = -2.f * Z;
        bd[u] = 1e30f; bi[u] = lane * 32;
    }
    const int qbase = lane * 32;
    for (int j = 0; j < 32; j++) {
        float4 t4 = tq[qbase + (j ^ (lane & 31))];
        int idx = qbase + j;
#pragma unroll
        for (int u = 0; u < 8; u++) {
            // d' = |t|^2 - 2 s.t (monotone in true distance)
            float d = fmaf(Tx[u], t4.x, fmaf(Ty[u], t4.y, fmaf(Tz[u], t4.z, t4.w)));
            if (d < bd[u]) { bd[u] = d; bi[u] = idx; }
        }
    }
#pragma unroll
    for (int u = 0; u < 8; u++) {
        int row = wave * 8 + u;
        sm_d[row * 65 + lane] = bd[u];
        sm_i[row * 65 + lane] = (unsigned short)bi[u];
        if (lane == u) { ssx[row] = Sx[u]; ssy[row] = Sy[u]; ssz[row] = Sz[u]; }
    }
    __syncthreads();
    // wave 0: per-src argmin (ranges ascend -> strict < keeps first index) + moments
    if (tid < 64) {
        const int s = tid;
        float best = sm_d[s * 65];
        int ib = sm_i[s * 65];
        for (int r = 1; r < 64; r++) {
            float dd = sm_d[s * 65 + r];
            int ii = sm_i[s * 65 + r];
            if (dd < best) { best = dd; ib = ii; }
        }
        float4 c = tq[swz32(ib)];
        float X = ssx[s], Y = ssy[s], Z = ssz[s];
        float vals[15] = { X, Y, Z, c.x, c.y, c.z,
                           X * c.x, X * c.y, X * c.z,
                           Y * c.x, Y * c.y, Y * c.z,
                           Z * c.x, Z * c.y, Z * c.z };
#pragma unroll
        for (int k = 0; k < 15; k++) {
            float v = vals[k];
            for (int o = 32; o > 0; o >>= 1) v += __shfl_down(v, o);
            if (tid == 0) Pout[(size_t)blockIdx.x * 16 + k] = v;   // plain store
        }
    }
}

// -------- chamfer: recompute T(10) (wave0), apply, bidirectional chamfer, loss ------------
__global__ __launch_bounds__(512) void k_chamfer_all(
    const float4* __restrict__ pos4, const float* __restrict__ tpos,
    const float* __restrict__ Pin, const double* __restrict__ TdIn,
    float* __restrict__ chpart, int* __restrict__ ctrs,
    float* __restrict__ out_aligned, float* __restrict__ out_loss)
{
    const int g = blockIdx.x >> 5, blk = blockIdx.x & 31;
    const int tid = threadIdx.x;
    const int wave = tid >> 6, lane = tid & 63;
    __shared__ float4 tq[NPG_];
    __shared__ float4 al[NPG_];
    __shared__ float wred[8][2];
    __shared__ float Tsh[12];
    __shared__ int lastFlag;

    for (int i = tid; i < NPG_; i += 512)
        tq[swz32(i)] = pos4[(size_t)g * NPG_ + i];
    if (wave == 0)
        compute_T_wave0(lane, g, ICP_IT, Pin, TdIn + g * 12, nullptr, Tsh, 0, 0);
    __syncthreads();

    float Tf[12];
#pragma unroll
    for (int k = 0; k < 12; k++) Tf[k] = Tsh[k];
    for (int i = tid; i < NPG_; i += 512) {
        const float* q = &tpos[(size_t)(g * NPG_ + i) * 3];
        float X = Tf[0] * q[0] + Tf[1] * q[1] + Tf[2] * q[2] + Tf[9];
        float Y = Tf[3] * q[0] + Tf[4] * q[1] + Tf[5] * q[2] + Tf[10];
        float Z = Tf[6] * q[0] + Tf[7] * q[1] + Tf[8] * q[2] + Tf[11];
        al[swz32(i)] = make_float4(X, Y, Z, fmaf(X, X, fmaf(Y, Y, Z * Z)));
        if (blk == 0) {
            out_aligned[(size_t)(g * NPG_ + i) * 3 + 0] = X;
            out_aligned[(size_t)(g * NPG_ + i) * 3 + 1] = Y;
            out_aligned[(size_t)(g * NPG_ + i) * 3 + 2] = Z;
        }
    }
    __syncthreads();
    float Ax[8], Ay[8], Az[8], Aw[8], Qx[8], Qy[8], Qz[8], Qw[8], d1[8], d2[8];
#pragma unroll
    for (int u = 0; u < 8; u++) {
        int s = swz32(blk * 64 + wave * 8 + u);
        float4 a4 = al[s]; float4 p4 = tq[s];
        Ax[u] = -2.f * a4.x; Ay[u] = -2.f * a4.y; Az[u] = -2.f * a4.z; Aw[u] = a4.w;
        Qx[u] = -2.f * p4.x; Qy[u] = -2.f * p4.y; Qz[u] = -2.f * p4.z; Qw[u] = p4.w;
        d1[u] = 1e30f; d2[u] = 1e30f;
    }
    const int qbase = lane * 32;
    for (int j = 0; j < 32; j++) {
        int s = qbase + (j ^ (lane & 31));
        float4 t4 = tq[s];
        float4 b4 = al[s];
#pragma unroll
        for (int u = 0; u < 8; u++) {
            d1[u] = fminf(d1[u], fmaf(Ax[u], t4.x, fmaf(Ay[u], t4.y, fmaf(Az[u], t4.z, t4.w))));
            d2[u] = fminf(d2[u], fmaf(Qx[u], b4.x, fmaf(Qy[u], b4.y, fmaf(Qz[u], b4.z, b4.w))));
        }
    }
    float s1 = 0.f, s2 = 0.f;
#pragma unroll
    for (int u = 0; u < 8; u++) {
        float a = d1[u], b = d2[u];
        for (int o = 32; o > 0; o >>= 1) {
            a = fminf(a, __shfl_down(a, o));
            b = fminf(b, __shfl_down(b, o));
        }
        s1 += a + Aw[u];     // + |src|^2 completes squared distance
        s2 += b + Qw[u];
    }
    if (lane == 0) { wred[wave][0] = s1; wred[wave][1] = s2; }
    __syncthreads();
    if (tid == 0) {
        float t1 = 0.f, t2 = 0.f;
#pragma unroll
        for (int w = 0; w < 8; w++) { t1 += wred[w][0]; t2 += wred[w][1]; }
        st_agent(&chpart[blockIdx.x * 2 + 0], t1);
        st_agent(&chpart[blockIdx.x * 2 + 1], t2);
    }
    __syncthreads();
    if (tid == 0) {
        int old = atomicAdd(&ctrs[0], 1);
        lastFlag = (old == (int)gridDim.x - 1) ? 1 : 0;
    }
    __syncthreads();
    if (!lastFlag) return;
    float v1 = 0.f, v2 = 0.f;
    if (tid < 256) {
        v1 = ld_agent(&chpart[tid * 2 + 0]);
        v2 = ld_agent(&chpart[tid * 2 + 1]);
    }
    for (int o = 32; o > 0; o >>= 1) {
        v1 += __shfl_down(v1, o);
        v2 += __shfl_down(v2, o);
    }
    if (lane == 0 && wave < 4) { wred[wave][0] = v1; wred[wave][1] = v2; }
    __syncthreads();
    if (tid == 0) {
        float tot = 0.f;
#pragma unroll
        for (int w = 0; w < 4; w++) tot += wred[w][0] + wred[w][1];
        out_loss[0] = tot / (float)(NPG_ * B_GRAPHS);
    }
}

// ---------------- launcher ----------------
extern "C" void kernel_launch(void* const* d_in, const int* in_sizes, int n_in,
                              void* d_out, int out_size, void* d_ws, size_t ws_size,
                              hipStream_t stream)
{
    (void)in_sizes; (void)n_in; (void)out_size; (void)ws_size;
    const float* x   = (const float*)d_in[0];
    const int*   ei  = (const int*)d_in[1];
    const float* pos = (const float*)d_in[2];
    const float* W1 = (const float*)d_in[4];
    const float* b1 = (const float*)d_in[5];
    const float* W2 = (const float*)d_in[6];
    const float* b2 = (const float*)d_in[7];
    const float* W3 = (const float*)d_in[8];
    const float* b3 = (const float*)d_in[9];
    const float* Wt = (const float*)d_in[10];
    const float* bt = (const float*)d_in[11];
    const int* row = ei;
    const int* col = ei + E_EDGES;

    char* wsb = (char*)d_ws;
    size_t off_b = 0;
    auto alloc = [&](size_t bytes) -> void* {
        void* p = wsb + off_b;
        off_b = (off_b + bytes + 255) & ~(size_t)255;
        return p;
    };
    // contiguous zero region: counts (64KB) + ctrs (1KB)
    int*    counts   = (int*)alloc((size_t)N_NODES * 4);
    int*    ctrs     = (int*)alloc((size_t)256 * 4);
    float4* pos4     = (float4*)alloc((size_t)N_NODES * 16);
    float*  Pbuf     = (float*)alloc((size_t)2 * 256 * 16 * 4);
    double* Td_arr   = (double*)alloc((size_t)ICP_IT * B_GRAPHS * 12 * 8);
    int*    offs     = (int*)alloc((size_t)(N_NODES + 1) * 4);
    int*    cursor   = (int*)alloc((size_t)N_NODES * 4);
    int*    srcid    = (int*)alloc((size_t)E_EDGES * 4);
    float*  normv    = (float*)alloc((size_t)E_EDGES * 4);
    float*  dinv     = (float*)alloc((size_t)N_NODES * 4);
    unsigned short* xb  = (unsigned short*)alloc((size_t)N_NODES * F_IN * 2);
    unsigned short* W1b = (unsigned short*)alloc((size_t)F_IN * F_HID * 2);
    unsigned short* W2b = (unsigned short*)alloc((size_t)F_HID * F_HID * 2);
    unsigned short* W3b = (unsigned short*)alloc((size_t)F_HID * F_OUT * 2);
    unsigned short* bufA = (unsigned short*)alloc((size_t)N_NODES * F_HID * 2);
    unsigned short* bufB = (unsigned short*)alloc((size_t)N_NODES * F_HID * 2);
    unsigned short* bufC = (unsigned short*)alloc((size_t)N_NODES * F_HID * 2);
    float*  tpos     = (float*)alloc((size_t)N_NODES * 3 * 4);
    float*  chpart   = (float*)alloc((size_t)256 * 2 * 4);

    float* out_h       = (float*)d_out;
    float* out_aligned = out_h + (size_t)N_NODES * F_OUT;
    float* out_loss    = out_aligned + (size_t)N_NODES * 3;

    // 1: zero counts + ctrs (stream-ordered, replay-safe)
    hipMemsetAsync(counts, 0, (size_t)N_NODES * 4 + 256 * 4, stream);
    // 2: converts + pos4 + edge count
    k_prep<<<3648, 256, 0, stream>>>(x, xb, pos, pos4, W1, W2, W3, W1b, W2b, W3b, col, counts);
    // 3-4: CSR
    k_scan<<<1, 1024, 0, stream>>>(counts, offs, cursor, dinv);
    k_scatter<<<E_EDGES / 256, 256, 0, stream>>>(row, col, cursor, dinv, srcid, normv);

    // 5: layer1 aggregate (x bf16 -> bufA)
    k_agg128<0, 0><<<N_NODES / 2, 128, 0, stream>>>(xb, bufA, offs, srcid, normv, dinv,
            nullptr, 0, nullptr, nullptr, nullptr, nullptr);
    // 6: gemm1 + bias + relu
    {
        dim3 grid(F_HID / 64, N_NODES / 128);
        k_gemm_bf16<<<grid, 256, 0, stream>>>(bufA, W1b, b1, bufB, N_NODES, F_HID, F_IN, 1);
    }
    // 7: gemm2 (no bias)
    {
        dim3 grid(F_HID / 64, N_NODES / 128);
        k_gemm_bf16<<<grid, 256, 0, stream>>>(bufB, W2b, nullptr, bufC, N_NODES, F_HID, F_HID, 0);
    }
    // 8: layer2 aggregate + b2 + relu
    k_agg256<<<N_NODES / 2, 128, 0, stream>>>(bufC, bufA, offs, srcid, normv, dinv, b2, 1);
    // 9: gemm3
    {
        dim3 grid(F_OUT / 64, N_NODES / 128);
        k_gemm_bf16<<<grid, 256, 0, stream>>>(bufA, W3b, nullptr, bufB, N_NODES, F_OUT, F_HID, 0);
    }
    // 10: layer3 aggregate + b3 -> out_h (fp32), fused tpos
    k_agg128<1, 1><<<N_NODES / 2, 128, 0, stream>>>(bufB, out_h, offs, srcid, normv, dinv,
            b3, 0, Wt, bt, pos, tpos);

    // 11-20: ICP, one launch per iteration (kernel boundary = global sync)
    for (int j = 0; j < ICP_IT; ++j) {
        const float* Pin  = Pbuf + (size_t)((j + 1) & 1) * 256 * 16;  // prev (unused j=0)
        float*       Pout = Pbuf + (size_t)(j & 1) * 256 * 16;
        const double* TdIn = Td_arr + (size_t)(j > 0 ? j - 1 : 0) * B_GRAPHS * 12;
        double*       TdOut = Td_arr + (size_t)j * B_GRAPHS * 12;
        k_icp_nn<<<256, 512, 0, stream>>>(pos4, tpos, Pin, Pout, TdIn, TdOut, j);
    }
    // 21: T(10) + apply + chamfer + loss
    k_chamfer_all<<<256, 512, 0, stream>>>(pos4, tpos,
            Pbuf + (size_t)((ICP_IT - 1) & 1) * 256 * 16,
            Td_arr + (size_t)(ICP_IT - 1) * B_GRAPHS * 12,
            chpart, ctrs, out_aligned, out_loss);
}

// Round 13
// 289.352 us; speedup vs baseline: 1.1141x; 1.0346x over previous
//
#include <hip/hip_runtime.h>
#include <math.h>

#define N_NODES 16384
#define B_GRAPHS 8
#define NPG_     2048
#define E_EDGES  262144
#define F_IN  128
#define F_HID 256
#define F_OUT 128
#define ICP_IT 10

typedef __attribute__((ext_vector_type(8))) short bf16x8;
typedef __attribute__((ext_vector_type(4))) float f32x4;

__device__ __forceinline__ float b2f(unsigned short u) {
    union { unsigned int u; float f; } v; v.u = ((unsigned int)u) << 16; return v.f;
}
__device__ __forceinline__ unsigned short f2b(float f) {
    union { float f; unsigned int u; } v; v.f = f;
    unsigned int r = v.u + 0x7FFFu + ((v.u >> 16) & 1u);
    return (unsigned short)(r >> 16);
}
// XOR swizzle within 32-element groups: spreads lane-sliced LDS scans over banks.
__device__ __forceinline__ int swz32(int i) {
    return (i & ~31) | ((i & 31) ^ ((i >> 5) & 31));
}
// Agent-scope accesses (used ONLY in chamfer last-block loss; validated R4-R10).
__device__ __forceinline__ void st_agent(float* p, float v) {
    __hip_atomic_store(p, v, __ATOMIC_RELAXED, __HIP_MEMORY_SCOPE_AGENT);
}
__device__ __forceinline__ float ld_agent(const float* p) {
    return __hip_atomic_load(p, __ATOMIC_RELAXED, __HIP_MEMORY_SCOPE_AGENT);
}

// ---- Kabsch: moments -> incremental R,t -> compose with Tp (lane-local, fp64 I/O) -------
__device__ void kabsch_update(const double sd[15], const double Tp[12], double Tn[12])
{
    const double n = (double)NPG_;
    const double rin = 1.0 / n;
    double cs0 = sd[0]*rin, cs1 = sd[1]*rin, cs2 = sd[2]*rin;
    double cc0 = sd[3]*rin, cc1 = sd[4]*rin, cc2 = sd[5]*rin;
    float H[3][3];
    H[0][0] = (float)(sd[6]  - n*cs0*cc0); H[0][1] = (float)(sd[7]  - n*cs0*cc1); H[0][2] = (float)(sd[8]  - n*cs0*cc2);
    H[1][0] = (float)(sd[9]  - n*cs1*cc0); H[1][1] = (float)(sd[10] - n*cs1*cc1); H[1][2] = (float)(sd[11] - n*cs1*cc2);
    H[2][0] = (float)(sd[12] - n*cs2*cc0); H[2][1] = (float)(sd[13] - n*cs2*cc1); H[2][2] = (float)(sd[14] - n*cs2*cc2);
    double R[3][3];
    float fn = 1e-30f;
    for (int i = 0; i < 3; i++) for (int j = 0; j < 3; j++) fn += H[i][j] * H[i][j];
    float sc = rsqrtf(fn);
    float Xm[3][3];
    for (int i = 0; i < 3; i++) for (int j = 0; j < 3; j++) Xm[i][j] = H[i][j] * sc;
    float dX = Xm[0][0]*(Xm[1][1]*Xm[2][2]-Xm[1][2]*Xm[2][1])
             - Xm[0][1]*(Xm[1][0]*Xm[2][2]-Xm[1][2]*Xm[2][0])
             + Xm[0][2]*(Xm[1][0]*Xm[2][1]-Xm[1][1]*Xm[2][0]);
    if (dX > 1e-4f) {
        // polar Newton: X <- 0.5*(X + cof(X)/det(X)); R_ref = Q^T  (converged by ~8 iters)
        for (int itn = 0; itn < 10; ++itn) {
            float C00 = Xm[1][1]*Xm[2][2]-Xm[1][2]*Xm[2][1];
            float C01 = Xm[1][2]*Xm[2][0]-Xm[1][0]*Xm[2][2];
            float C02 = Xm[1][0]*Xm[2][1]-Xm[1][1]*Xm[2][0];
            float C10 = Xm[2][1]*Xm[0][2]-Xm[2][2]*Xm[0][1];
            float C11 = Xm[2][2]*Xm[0][0]-Xm[2][0]*Xm[0][2];
            float C12 = Xm[2][0]*Xm[0][1]-Xm[2][1]*Xm[0][0];
            float C20 = Xm[0][1]*Xm[1][2]-Xm[0][2]*Xm[1][1];
            float C21 = Xm[0][2]*Xm[1][0]-Xm[0][0]*Xm[1][2];
            float C22 = Xm[0][0]*Xm[1][1]-Xm[0][1]*Xm[1][0];
            float det = Xm[0][0]*C00 + Xm[0][1]*C01 + Xm[0][2]*C02;
            if (fabsf(det) < 1e-30f) break;
            float rd = 0.5f / det;
            Xm[0][0]=0.5f*Xm[0][0]+C00*rd; Xm[0][1]=0.5f*Xm[0][1]+C01*rd; Xm[0][2]=0.5f*Xm[0][2]+C02*rd;
            Xm[1][0]=0.5f*Xm[1][0]+C10*rd; Xm[1][1]=0.5f*Xm[1][1]+C11*rd; Xm[1][2]=0.5f*Xm[1][2]+C12*rd;
            Xm[2][0]=0.5f*Xm[2][0]+C20*rd; Xm[2][1]=0.5f*Xm[2][1]+C21*rd; Xm[2][2]=0.5f*Xm[2][2]+C22*rd;
        }
        for (int i = 0; i < 3; i++) for (int j = 0; j < 3; j++) R[i][j] = (double)Xm[j][i];
    } else {
        // Jacobi-SVD fallback (deterministic)
        float A[3][3], V[3][3] = {{1,0,0},{0,1,0},{0,0,1}};
        for (int i = 0; i < 3; i++)
            for (int j = 0; j < 3; j++)
                A[i][j] = H[0][i]*H[0][j] + H[1][i]*H[1][j] + H[2][i]*H[2][j];
        for (int sweep = 0; sweep < 8; ++sweep) {
            for (int p = 0; p < 2; p++) for (int q = p + 1; q < 3; q++) {
                float apq = A[p][q];
                if (fabsf(apq) < 1e-30f) continue;
                float theta = (A[q][q] - A[p][p]) / (2.f * apq);
                float t = copysignf(1.f, theta) / (fabsf(theta) + sqrtf(theta*theta + 1.f));
                float c = 1.f / sqrtf(t*t + 1.f);
                float s = t * c;
                for (int k = 0; k < 3; k++) { float akp=A[k][p], akq=A[k][q]; A[k][p]=c*akp-s*akq; A[k][q]=s*akp+c*akq; }
                for (int k = 0; k < 3; k++) { float apk=A[p][k], aqk=A[q][k]; A[p][k]=c*apk-s*aqk; A[q][k]=s*apk+c*aqk; }
                for (int k = 0; k < 3; k++) { float vkp=V[k][p], vkq=V[k][q]; V[k][p]=c*vkp-s*vkq; V[k][q]=s*vkp+c*vkq; }
            }
        }
        float lam[3] = { A[0][0], A[1][1], A[2][2] };
        int ord[3] = { 0, 1, 2 };
        if (lam[ord[1]] > lam[ord[0]]) { int t0=ord[0]; ord[0]=ord[1]; ord[1]=t0; }
        if (lam[ord[2]] > lam[ord[0]]) { int t0=ord[0]; ord[0]=ord[2]; ord[2]=t0; }
        if (lam[ord[2]] > lam[ord[1]]) { int t0=ord[1]; ord[1]=ord[2]; ord[2]=t0; }
        float vc[3][3], uc[3][3];
        for (int i = 0; i < 3; i++) { vc[i][0]=V[0][ord[i]]; vc[i][1]=V[1][ord[i]]; vc[i][2]=V[2][ord[i]]; }
        for (int i = 0; i < 3; i++) {
            float u0 = H[0][0]*vc[i][0] + H[0][1]*vc[i][1] + H[0][2]*vc[i][2];
            float u1 = H[1][0]*vc[i][0] + H[1][1]*vc[i][1] + H[1][2]*vc[i][2];
            float u2 = H[2][0]*vc[i][0] + H[2][1]*vc[i][1] + H[2][2]*vc[i][2];
            for (int j = 0; j < i; j++) {
                float dp = u0*uc[j][0] + u1*uc[j][1] + u2*uc[j][2];
                u0 -= dp*uc[j][0]; u1 -= dp*uc[j][1]; u2 -= dp*uc[j][2];
            }
            float nn2 = sqrtf(u0*u0 + u1*u1 + u2*u2);
            if (nn2 > 1e-12f) { uc[i][0]=u0/nn2; uc[i][1]=u1/nn2; uc[i][2]=u2/nn2; }
            else if (i == 2) {
                uc[2][0]=uc[0][1]*uc[1][2]-uc[0][2]*uc[1][1];
                uc[2][1]=uc[0][2]*uc[1][0]-uc[0][0]*uc[1][2];
                uc[2][2]=uc[0][0]*uc[1][1]-uc[0][1]*uc[1][0];
            } else if (i == 1) {
                float a0 = (fabsf(uc[0][0]) < 0.9f) ? 1.f : 0.f, a1 = 1.f - a0, a2 = 0.f;
                float dp = a0*uc[0][0] + a1*uc[0][1] + a2*uc[0][2];
                a0 -= dp*uc[0][0]; a1 -= dp*uc[0][1]; a2 -= dp*uc[0][2];
                float nn3 = sqrtf(a0*a0 + a1*a1 + a2*a2);
                uc[1][0]=a0/nn3; uc[1][1]=a1/nn3; uc[1][2]=a2/nn3;
            } else { uc[0][0]=1; uc[0][1]=0; uc[0][2]=0; }
        }
        float detU = uc[0][0]*(uc[1][1]*uc[2][2]-uc[1][2]*uc[2][1])
                   - uc[0][1]*(uc[1][0]*uc[2][2]-uc[1][2]*uc[2][0])
                   + uc[0][2]*(uc[1][0]*uc[2][1]-uc[1][1]*uc[2][0]);
        float detV = vc[0][0]*(vc[1][1]*vc[2][2]-vc[1][2]*vc[2][1])
                   - vc[0][1]*(vc[1][0]*vc[2][2]-vc[1][2]*vc[2][0])
                   + vc[0][2]*(vc[1][0]*vc[2][1]-vc[1][1]*vc[2][0]);
        float sgn = (detU * detV < 0.f) ? -1.f : 1.f;
        for (int i = 0; i < 3; i++)
            for (int j = 0; j < 3; j++)
                R[i][j] = (double)(vc[0][i]*uc[0][j] + vc[1][i]*uc[1][j] + sgn*vc[2][i]*uc[2][j]);
    }
    double tr0 = cc0 - (R[0][0]*cs0 + R[0][1]*cs1 + R[0][2]*cs2);
    double tr1 = cc1 - (R[1][0]*cs0 + R[1][1]*cs1 + R[1][2]*cs2);
    double tr2 = cc2 - (R[2][0]*cs0 + R[2][1]*cs1 + R[2][2]*cs2);
    for (int i = 0; i < 3; i++)
        for (int j = 0; j < 3; j++)
            Tn[i*3+j] = R[i][0]*Tp[0*3+j] + R[i][1]*Tp[1*3+j] + R[i][2]*Tp[2*3+j];
    Tn[9]  = R[0][0]*Tp[9] + R[0][1]*Tp[10] + R[0][2]*Tp[11] + tr0;
    Tn[10] = R[1][0]*Tp[9] + R[1][1]*Tp[10] + R[1][2]*Tp[11] + tr1;
    Tn[11] = R[2][0]*Tp[9] + R[2][1]*Tp[10] + R[2][2]*Tp[11] + tr2;
}

// Wave-0 helper: gather 32x15 partials (plain cached), tree-sum, compute Tsh (+opt TdOut).
__device__ void compute_T_wave0(int lane, int g, int iter,
        const float* __restrict__ Pin, const double* __restrict__ TdIn,
        double* __restrict__ TdOut, float* Tsh, int writeTd, int isBlock0)
{
    if (iter == 0) {
        if (lane < 12) Tsh[lane] = (lane == 0 || lane == 4 || lane == 8) ? 1.f : 0.f;
        return;
    }
    double sd[15];
#pragma unroll
    for (int k = 0; k < 15; k++) sd[k] = 0.0;
    if (lane < 32) {
        const float* lp = Pin + ((size_t)g * 32 + lane) * 16;
#pragma unroll
        for (int k = 0; k < 15; k++) sd[k] = (double)lp[k];
    }
#pragma unroll
    for (int k = 0; k < 15; k++)
        for (int o = 16; o > 0; o >>= 1) sd[k] += __shfl_down(sd[k], o);
    if (lane == 0) {
        double Tp[12], Tn[12];
        if (iter == 1) {
#pragma unroll
            for (int k = 0; k < 12; k++) Tp[k] = (k == 0 || k == 4 || k == 8) ? 1.0 : 0.0;
        } else {
#pragma unroll
            for (int k = 0; k < 12; k++) Tp[k] = TdIn[k];
        }
        kabsch_update(sd, Tp, Tn);
#pragma unroll
        for (int k = 0; k < 12; k++) Tsh[k] = (float)Tn[k];
        if (writeTd && isBlock0) {
#pragma unroll
            for (int k = 0; k < 12; k++) TdOut[k] = Tn[k];
        }
    }
}

// ------- k_prep: x->bf16, pos4 precompute, weight transposes, edge count ------------------
__global__ __launch_bounds__(256) void k_prep(
    const float* __restrict__ x, unsigned short* __restrict__ xb,
    const float* __restrict__ pos, float4* __restrict__ pos4,
    const float* __restrict__ W1, const float* __restrict__ W2, const float* __restrict__ W3,
    unsigned short* __restrict__ W1b, unsigned short* __restrict__ W2b, unsigned short* __restrict__ W3b,
    const int* __restrict__ col, int* __restrict__ counts)
{
    const int b = blockIdx.x, tid = threadIdx.x;
    if (b < 2048) {                       // x: 524288 float4 -> uint2
        int i = b * 256 + tid;
        float4 v = ((const float4*)x)[i];
        uint2 o;
        o.x = (unsigned int)f2b(v.x) | ((unsigned int)f2b(v.y) << 16);
        o.y = (unsigned int)f2b(v.z) | ((unsigned int)f2b(v.w) << 16);
        ((uint2*)xb)[i] = o;
    } else if (b < 2112) {                // pos4 = (x,y,z,|p|^2)
        int i = (b - 2048) * 256 + tid;
        float px = pos[i*3], py = pos[i*3+1], pz = pos[i*3+2];
        pos4[i] = make_float4(px, py, pz, fmaf(px, px, fmaf(py, py, pz * pz)));
    } else if (b < 2240) {                // W1 [128][256] -> W1b [256][128]
        int idx = (b - 2112) * 256 + tid;
        int k = idx >> 8, n = idx & 255;
        W1b[n * 128 + k] = f2b(W1[idx]);
    } else if (b < 2496) {                // W2 [256][256] -> W2b [256][256]
        int idx = (b - 2240) * 256 + tid;
        int k = idx >> 8, n = idx & 255;
        W2b[n * 256 + k] = f2b(W2[idx]);
    } else if (b < 2624) {                // W3 [256][128] -> W3b [128][256]
        int idx = (b - 2496) * 256 + tid;
        int k = idx >> 7, n = idx & 127;
        W3b[n * 256 + k] = f2b(W3[idx]);
    } else {                              // edge in-degree count
        int e = (b - 2624) * 256 + tid;
        atomicAdd(&counts[col[e]], 1);
    }
}

// ---------------- CSR build ----------------
__global__ __launch_bounds__(1024) void k_scan(const int* __restrict__ counts,
        int* __restrict__ offs, int* __restrict__ cursor, float* __restrict__ dinv)
{
    __shared__ int wtot[16];
    const int t = threadIdx.x;
    const int base = t * 16;
    int local[16];
    int s = 0;
#pragma unroll
    for (int i = 0; i < 16; i++) { local[i] = counts[base + i]; s += local[i]; }
    const int lane = t & 63, w = t >> 6;
    int inc = s;
    for (int o = 1; o < 64; o <<= 1) {
        int v = __shfl_up(inc, o);
        if (lane >= o) inc += v;
    }
    if (lane == 63) wtot[w] = inc;
    __syncthreads();
    if (t < 16) {
        int v = wtot[t];
        for (int o = 1; o < 16; o <<= 1) {
            int u = __shfl_up(v, o);
            if (t >= o) v += u;
        }
        wtot[t] = v;
    }
    __syncthreads();
    int run = (w > 0 ? wtot[w - 1] : 0) + (inc - s);
#pragma unroll
    for (int i = 0; i < 16; i++) {
        offs[base + i]   = run;
        cursor[base + i] = run;
        dinv[base + i]   = rsqrtf((float)(local[i] + 1));  // deg = indeg + self loop
        run += local[i];
    }
    if (t == 1023) offs[N_NODES] = run;
}

__global__ void k_scatter(const int* __restrict__ row, const int* __restrict__ col,
        int* __restrict__ cursor, const float* __restrict__ dinv,
        int* __restrict__ srcid, float* __restrict__ normv)
{
    int e = blockIdx.x * 256 + threadIdx.x;
    if (e >= E_EDGES) return;
    int r = row[e], c = col[e];
    int p = atomicAdd(&cursor[c], 1);
    srcid[p] = r;
    normv[p] = dinv[r] * dinv[c];
}

// ---------------- GCN aggregation W=128 (bf16 in, fp32 acc); unroll-8; fused tpos ---------
template<int OUTF, int FUSET>
__global__ __launch_bounds__(128) void k_agg128(const unsigned short* __restrict__ X,
        void* __restrict__ Y,
        const int* __restrict__ offs, const int* __restrict__ srcid,
        const float* __restrict__ normv, const float* __restrict__ dinv,
        const float* __restrict__ bias, int relu,
        const float* __restrict__ Wt, const float* __restrict__ bt,
        const float* __restrict__ pos, float* __restrict__ tposO)
{
    const int local = threadIdx.x >> 6;
    const int n = blockIdx.x * 2 + local;
    const int j = threadIdx.x & 63;
    const unsigned int* Xu = (const unsigned int*)X;
    float di = dinv[n];
    float w0 = di * di;
    unsigned int v = Xu[(size_t)n * 64 + j];
    float a0 = b2f((unsigned short)v) * w0;
    float a1 = b2f((unsigned short)(v >> 16)) * w0;
    int p = offs[n];
    const int p1 = offs[n + 1];
    // unroll-8: 8 outstanding row loads (ascending p order -> bit-identical sum)
    for (; p + 7 < p1; p += 8) {
        int si[8]; float nw[8]; unsigned int vv[8];
#pragma unroll
        for (int q = 0; q < 8; q++) { si[q] = srcid[p + q]; nw[q] = normv[p + q]; }
#pragma unroll
        for (int q = 0; q < 8; q++) vv[q] = Xu[(size_t)si[q] * 64 + j];
#pragma unroll
        for (int q = 0; q < 8; q++) {
            a0 = fmaf(b2f((unsigned short)vv[q]), nw[q], a0);
            a1 = fmaf(b2f((unsigned short)(vv[q] >> 16)), nw[q], a1);
        }
    }
    for (; p < p1; ++p) {
        unsigned int va = Xu[(size_t)srcid[p] * 64 + j]; float na = normv[p];
        a0 = fmaf(b2f((unsigned short)va), na, a0);
        a1 = fmaf(b2f((unsigned short)(va >> 16)), na, a1);
    }
    if (bias) { a0 += bias[2 * j]; a1 += bias[2 * j + 1]; }
    if (relu) { a0 = fmaxf(a0, 0.f); a1 = fmaxf(a1, 0.f); }
    if (OUTF) {
        float* Yf = (float*)Y;
        Yf[(size_t)n * 128 + 2 * j]     = a0;
        Yf[(size_t)n * 128 + 2 * j + 1] = a1;
    } else {
        ((unsigned int*)Y)[(size_t)n * 64 + j] =
            (unsigned int)f2b(a0) | ((unsigned int)f2b(a1) << 16);
    }
    if (FUSET) {
        float wt0 = Wt[6 * j + 0], wt1 = Wt[6 * j + 1], wt2 = Wt[6 * j + 2];
        float wt3 = Wt[6 * j + 3], wt4 = Wt[6 * j + 4], wt5 = Wt[6 * j + 5];
        float s0 = a0 * wt0 + a1 * wt3;
        float s1 = a0 * wt1 + a1 * wt4;
        float s2 = a0 * wt2 + a1 * wt5;
        for (int o = 32; o > 0; o >>= 1) {
            s0 += __shfl_down(s0, o);
            s1 += __shfl_down(s1, o);
            s2 += __shfl_down(s2, o);
        }
        if (j == 0) {
            tposO[n * 3 + 0] = pos[n * 3 + 0] + s0 + bt[0];
            tposO[n * 3 + 1] = pos[n * 3 + 1] + s1 + bt[1];
            tposO[n * 3 + 2] = pos[n * 3 + 2] + s2 + bt[2];
        }
    }
}

// ---------------- GCN aggregation W=256: one wave per node, uint2, unroll-8 ---------------
__global__ __launch_bounds__(128) void k_agg256(const unsigned short* __restrict__ X,
        unsigned short* __restrict__ Y,
        const int* __restrict__ offs, const int* __restrict__ srcid,
        const float* __restrict__ normv, const float* __restrict__ dinv,
        const float* __restrict__ bias, int relu)
{
    const int local = threadIdx.x >> 6;
    const int n = blockIdx.x * 2 + local;
    const int lane = threadIdx.x & 63;
    const uint2* Xu = (const uint2*)X;
    float di = dinv[n];
    float w0 = di * di;
    uint2 v = Xu[(size_t)n * 64 + lane];
    float a0 = b2f((unsigned short)v.x) * w0;
    float a1 = b2f((unsigned short)(v.x >> 16)) * w0;
    float a2 = b2f((unsigned short)v.y) * w0;
    float a3 = b2f((unsigned short)(v.y >> 16)) * w0;
    int p = offs[n];
    const int p1 = offs[n + 1];
    // unroll-8: 8 outstanding uint2 loads (ascending p order -> bit-identical sum)
    for (; p + 7 < p1; p += 8) {
        int si[8]; float nw[8]; uint2 vv[8];
#pragma unroll
        for (int q = 0; q < 8; q++) { si[q] = srcid[p + q]; nw[q] = normv[p + q]; }
#pragma unroll
        for (int q = 0; q < 8; q++) vv[q] = Xu[(size_t)si[q] * 64 + lane];
#pragma unroll
        for (int q = 0; q < 8; q++) {
            a0 = fmaf(b2f((unsigned short)vv[q].x), nw[q], a0);
            a1 = fmaf(b2f((unsigned short)(vv[q].x >> 16)), nw[q], a1);
            a2 = fmaf(b2f((unsigned short)vv[q].y), nw[q], a2);
            a3 = fmaf(b2f((unsigned short)(vv[q].y >> 16)), nw[q], a3);
        }
    }
    for (; p < p1; ++p) {
        uint2 va = Xu[(size_t)srcid[p] * 64 + lane]; float na = normv[p];
        a0 = fmaf(b2f((unsigned short)va.x), na, a0);
        a1 = fmaf(b2f((unsigned short)(va.x >> 16)), na, a1);
        a2 = fmaf(b2f((unsigned short)va.y), na, a2);
        a3 = fmaf(b2f((unsigned short)(va.y >> 16)), na, a3);
    }
    if (bias) {
        float4 bv = ((const float4*)bias)[lane];
        a0 += bv.x; a1 += bv.y; a2 += bv.z; a3 += bv.w;
    }
    if (relu) {
        a0 = fmaxf(a0, 0.f); a1 = fmaxf(a1, 0.f);
        a2 = fmaxf(a2, 0.f); a3 = fmaxf(a3, 0.f);
    }
    uint2 o;
    o.x = (unsigned int)f2b(a0) | ((unsigned int)f2b(a1) << 16);
    o.y = (unsigned int)f2b(a2) | ((unsigned int)f2b(a3) << 16);
    ((uint2*)Y)[(size_t)n * 64 + lane] = o;
}

// ---------------- bf16 MFMA GEMM: C[M,N] = A[M,K] @ Bt[N,K]^T (+bias,relu) ----------------
__global__ __launch_bounds__(256) void k_gemm_bf16(
    const unsigned short* __restrict__ A,   // [M][K] bf16
    const unsigned short* __restrict__ Bt,  // [N][K] bf16
    const float* __restrict__ bias, unsigned short* __restrict__ C,
    int M, int N, int K, int relu)
{
    __shared__ __align__(16) unsigned short As[128 * 64];
    __shared__ __align__(16) unsigned short Bs[64 * 64];
    const int tid  = threadIdx.x;
    const int lane = tid & 63;
    const int wave = tid >> 6;
    const int bm = blockIdx.y * 128, bn = blockIdx.x * 64;
    const int wm = (wave >> 1) * 64, wn = (wave & 1) * 32;
    f32x4 acc[4][2];
#pragma unroll
    for (int mf = 0; mf < 4; mf++)
#pragma unroll
        for (int nf = 0; nf < 2; nf++) acc[mf][nf] = (f32x4){0.f, 0.f, 0.f, 0.f};

    for (int k0 = 0; k0 < K; k0 += 64) {
#pragma unroll
        for (int i = 0; i < 4; i++) {
            int idx = i * 256 + tid;
            int m = idx >> 3, slot = idx & 7;
            const unsigned short* src = A + (size_t)(bm + m) * K + k0 + ((slot ^ (m & 7)) << 3);
            __builtin_amdgcn_global_load_lds(
                (const __attribute__((address_space(1))) unsigned int*)src,
                (__attribute__((address_space(3))) unsigned int*)(As + (size_t)i * 2048 + wave * 512),
                16, 0, 0);
        }
#pragma unroll
        for (int i = 0; i < 2; i++) {
            int idx = i * 256 + tid;
            int n = idx >> 3, slot = idx & 7;
            const unsigned short* src = Bt + (size_t)(bn + n) * K + k0 + ((slot ^ (n & 7)) << 3);
            __builtin_amdgcn_global_load_lds(
                (const __attribute__((address_space(1))) unsigned int*)src,
                (__attribute__((address_space(3))) unsigned int*)(Bs + (size_t)i * 2048 + wave * 512),
                16, 0, 0);
        }
        __syncthreads();
        bf16x8 af[4][2], bfr[2][2];
        const int qd = lane >> 4;
#pragma unroll
        for (int s = 0; s < 2; s++) {
#pragma unroll
            for (int mf = 0; mf < 4; mf++) {
                int m = wm + mf * 16 + (lane & 15);
                int slot = (s * 4 + qd) ^ (m & 7);
                af[mf][s] = *(const bf16x8*)(As + m * 64 + slot * 8);
            }
#pragma unroll
            for (int nf = 0; nf < 2; nf++) {
                int n = wn + nf * 16 + (lane & 15);
                int slot = (s * 4 + qd) ^ (n & 7);
                bfr[nf][s] = *(const bf16x8*)(Bs + n * 64 + slot * 8);
            }
        }
#pragma unroll
        for (int s = 0; s < 2; s++)
#pragma unroll
            for (int mf = 0; mf < 4; mf++)
#pragma unroll
                for (int nf = 0; nf < 2; nf++)
                    acc[mf][nf] = __builtin_amdgcn_mfma_f32_16x16x32_bf16(
                        af[mf][s], bfr[nf][s], acc[mf][nf], 0, 0, 0);
        __syncthreads();
    }
#pragma unroll
    for (int nf = 0; nf < 2; nf++) {
        int col = bn + wn + nf * 16 + (lane & 15);
        float bv = bias ? bias[col] : 0.f;
#pragma unroll
        for (int mf = 0; mf < 4; mf++) {
#pragma unroll
            for (int r = 0; r < 4; r++) {
                int row = bm + wm + mf * 16 + (lane >> 4) * 4 + r;
                float v = acc[mf][nf][r] + bv;
                if (relu) v = fmaxf(v, 0.f);
                C[(size_t)row * N + col] = f2b(v);
            }
        }
    }
}

// ---------------- ICP NN iteration (ONE launch per iteration; kernel boundary = sync) -----
__global__ __launch_bounds__(512) void k_icp_nn(
    const float4* __restrict__ pos4, const float* __restrict__ tpos,
    const float* __restrict__ Pin, float* __restrict__ Pout,     // [256][16] each
    const double* __restrict__ TdIn, double* __restrict__ TdOut, // [8][12] slices
    int iter)
{
    const int g = blockIdx.x >> 5, blk = blockIdx.x & 31;
    const int tid = threadIdx.x;
    const int wave = tid >> 6, lane = tid & 63;
    __shared__ float4 tq[NPG_];                                  // 32KB swizzled, w=|t|^2
    __shared__ float sm_d[64 * 65];
    __shared__ unsigned short sm_i[64 * 65];
    __shared__ float ssx[64], ssy[64], ssz[64];
    __shared__ float Tsh[12];

    for (int i = tid; i < NPG_; i += 512)
        tq[swz32(i)] = pos4[(size_t)g * NPG_ + i];
    float Px[8], Py[8], Pz[8];
#pragma unroll
    for (int u = 0; u < 8; u++) {
        int n = g * NPG_ + blk * 64 + wave * 8 + u;
        Px[u] = tpos[n * 3 + 0]; Py[u] = tpos[n * 3 + 1]; Pz[u] = tpos[n * 3 + 2];
    }
    if (wave == 0)
        compute_T_wave0(lane, g, iter, Pin, TdIn + g * 12, TdOut + g * 12, Tsh,
                        iter > 0, blk == 0);
    __syncthreads();

    float Tf[12];
#pragma unroll
    for (int k = 0; k < 12; k++) Tf[k] = Tsh[k];
    float Sx[8], Sy[8], Sz[8], Tx[8], Ty[8], Tz[8], bd[8];
    int bi[8];
#pragma unroll
    for (int u = 0; u < 8; u++) {
        float X = Tf[0] * Px[u] + Tf[1] * Py[u] + Tf[2] * Pz[u] + Tf[9];
        float Y = Tf[3] * Px[u] + Tf[4] * Py[u] + Tf[5] * Pz[u] + Tf[10];
        float Z = Tf[6] * Px[u] + Tf[7] * Py[u] + Tf[8] * Pz[u] + Tf[11];
        Sx[u] = X; Sy[u] = Y; Sz[u] = Z;
        Tx[u] = -2.f * X; Ty[u] = -2.f * Y; Tz[u] = -2.f * Z;
        bd[u] = 1e30f; bi[u] = lane * 32;
    }
    const int qbase = lane * 32;
    for (int j = 0; j < 32; j++) {
        float4 t4 = tq[qbase + (j ^ (lane & 31))];
        int idx = qbase + j;
#pragma unroll
        for (int u = 0; u < 8; u++) {
            // d' = |t|^2 - 2 s.t (monotone in true distance)
            float d = fmaf(Tx[u], t4.x, fmaf(Ty[u], t4.y, fmaf(Tz[u], t4.z, t4.w)));
            if (d < bd[u]) { bd[u] = d; bi[u] = idx; }
        }
    }
#pragma unroll
    for (int u = 0; u < 8; u++) {
        int row = wave * 8 + u;
        sm_d[row * 65 + lane] = bd[u];
        sm_i[row * 65 + lane] = (unsigned short)bi[u];
        if (lane == u) { ssx[row] = Sx[u]; ssy[row] = Sy[u]; ssz[row] = Sz[u]; }
    }
    __syncthreads();
    // wave 0: per-src argmin (ranges ascend -> strict < keeps first index) + moments
    if (tid < 64) {
        const int s = tid;
        float best = sm_d[s * 65];
        int ib = sm_i[s * 65];
        for (int r = 1; r < 64; r++) {
            float dd = sm_d[s * 65 + r];
            int ii = sm_i[s * 65 + r];
            if (dd < best) { best = dd; ib = ii; }
        }
        float4 c = tq[swz32(ib)];
        float X = ssx[s], Y = ssy[s], Z = ssz[s];
        float vals[15] = { X, Y, Z, c.x, c.y, c.z,
                           X * c.x, X * c.y, X * c.z,
                           Y * c.x, Y * c.y, Y * c.z,
                           Z * c.x, Z * c.y, Z * c.z };
#pragma unroll
        for (int k = 0; k < 15; k++) {
            float v = vals[k];
            for (int o = 32; o > 0; o >>= 1) v += __shfl_down(v, o);
            if (tid == 0) Pout[(size_t)blockIdx.x * 16 + k] = v;   // plain store
        }
    }
}

// -------- chamfer: recompute T(10) (wave0), apply, bidirectional chamfer, loss ------------
__global__ __launch_bounds__(512) void k_chamfer_all(
    const float4* __restrict__ pos4, const float* __restrict__ tpos,
    const float* __restrict__ Pin, const double* __restrict__ TdIn,
    float* __restrict__ chpart, int* __restrict__ ctrs,
    float* __restrict__ out_aligned, float* __restrict__ out_loss)
{
    const int g = blockIdx.x >> 5, blk = blockIdx.x & 31;
    const int tid = threadIdx.x;
    const int wave = tid >> 6, lane = tid & 63;
    __shared__ float4 tq[NPG_];
    __shared__ float4 al[NPG_];
    __shared__ float wred[8][2];
    __shared__ float Tsh[12];
    __shared__ int lastFlag;

    for (int i = tid; i < NPG_; i += 512)
        tq[swz32(i)] = pos4[(size_t)g * NPG_ + i];
    if (wave == 0)
        compute_T_wave0(lane, g, ICP_IT, Pin, TdIn + g * 12, nullptr, Tsh, 0, 0);
    __syncthreads();

    float Tf[12];
#pragma unroll
    for (int k = 0; k < 12; k++) Tf[k] = Tsh[k];
    for (int i = tid; i < NPG_; i += 512) {
        const float* q = &tpos[(size_t)(g * NPG_ + i) * 3];
        float X = Tf[0] * q[0] + Tf[1] * q[1] + Tf[2] * q[2] + Tf[9];
        float Y = Tf[3] * q[0] + Tf[4] * q[1] + Tf[5] * q[2] + Tf[10];
        float Z = Tf[6] * q[0] + Tf[7] * q[1] + Tf[8] * q[2] + Tf[11];
        al[swz32(i)] = make_float4(X, Y, Z, fmaf(X, X, fmaf(Y, Y, Z * Z)));
        if (blk == 0) {
            out_aligned[(size_t)(g * NPG_ + i) * 3 + 0] = X;
            out_aligned[(size_t)(g * NPG_ + i) * 3 + 1] = Y;
            out_aligned[(size_t)(g * NPG_ + i) * 3 + 2] = Z;
        }
    }
    __syncthreads();
    float Ax[8], Ay[8], Az[8], Aw[8], Qx[8], Qy[8], Qz[8], Qw[8], d1[8], d2[8];
#pragma unroll
    for (int u = 0; u < 8; u++) {
        int s = swz32(blk * 64 + wave * 8 + u);
        float4 a4 = al[s]; float4 p4 = tq[s];
        Ax[u] = -2.f * a4.x; Ay[u] = -2.f * a4.y; Az[u] = -2.f * a4.z; Aw[u] = a4.w;
        Qx[u] = -2.f * p4.x; Qy[u] = -2.f * p4.y; Qz[u] = -2.f * p4.z; Qw[u] = p4.w;
        d1[u] = 1e30f; d2[u] = 1e30f;
    }
    const int qbase = lane * 32;
    for (int j = 0; j < 32; j++) {
        int s = qbase + (j ^ (lane & 31));
        float4 t4 = tq[s];
        float4 b4 = al[s];
#pragma unroll
        for (int u = 0; u < 8; u++) {
            d1[u] = fminf(d1[u], fmaf(Ax[u], t4.x, fmaf(Ay[u], t4.y, fmaf(Az[u], t4.z, t4.w))));
            d2[u] = fminf(d2[u], fmaf(Qx[u], b4.x, fmaf(Qy[u], b4.y, fmaf(Qz[u], b4.z, b4.w))));
        }
    }
    float s1 = 0.f, s2 = 0.f;
#pragma unroll
    for (int u = 0; u < 8; u++) {
        float a = d1[u], b = d2[u];
        for (int o = 32; o > 0; o >>= 1) {
            a = fminf(a, __shfl_down(a, o));
            b = fminf(b, __shfl_down(b, o));
        }
        s1 += a + Aw[u];     // + |src|^2 completes squared distance
        s2 += b + Qw[u];
    }
    if (lane == 0) { wred[wave][0] = s1; wred[wave][1] = s2; }
    __syncthreads();
    if (tid == 0) {
        float t1 = 0.f, t2 = 0.f;
#pragma unroll
        for (int w = 0; w < 8; w++) { t1 += wred[w][0]; t2 += wred[w][1]; }
        st_agent(&chpart[blockIdx.x * 2 + 0], t1);
        st_agent(&chpart[blockIdx.x * 2 + 1], t2);
    }
    __syncthreads();
    if (tid == 0) {
        int old = atomicAdd(&ctrs[0], 1);
        lastFlag = (old == (int)gridDim.x - 1) ? 1 : 0;
    }
    __syncthreads();
    if (!lastFlag) return;
    float v1 = 0.f, v2 = 0.f;
    if (tid < 256) {
        v1 = ld_agent(&chpart[tid * 2 + 0]);
        v2 = ld_agent(&chpart[tid * 2 + 1]);
    }
    for (int o = 32; o > 0; o >>= 1) {
        v1 += __shfl_down(v1, o);
        v2 += __shfl_down(v2, o);
    }
    if (lane == 0 && wave < 4) { wred[wave][0] = v1; wred[wave][1] = v2; }
    __syncthreads();
    if (tid == 0) {
        float tot = 0.f;
#pragma unroll
        for (int w = 0; w < 4; w++) tot += wred[w][0] + wred[w][1];
        out_loss[0] = tot / (float)(NPG_ * B_GRAPHS);
    }
}

// ---------------- launcher ----------------
extern "C" void kernel_launch(void* const* d_in, const int* in_sizes, int n_in,
                              void* d_out, int out_size, void* d_ws, size_t ws_size,
                              hipStream_t stream)
{
    (void)in_sizes; (void)n_in; (void)out_size; (void)ws_size;
    const float* x   = (const float*)d_in[0];
    const int*   ei  = (const int*)d_in[1];
    const float* pos = (const float*)d_in[2];
    const float* W1 = (const float*)d_in[4];
    const float* b1 = (const float*)d_in[5];
    const float* W2 = (const float*)d_in[6];
    const float* b2 = (const float*)d_in[7];
    const float* W3 = (const float*)d_in[8];
    const float* b3 = (const float*)d_in[9];
    const float* Wt = (const float*)d_in[10];
    const float* bt = (const float*)d_in[11];
    const int* row = ei;
    const int* col = ei + E_EDGES;

    char* wsb = (char*)d_ws;
    size_t off_b = 0;
    auto alloc = [&](size_t bytes) -> void* {
        void* p = wsb + off_b;
        off_b = (off_b + bytes + 255) & ~(size_t)255;
        return p;
    };
    // contiguous zero region: counts (64KB) + ctrs (1KB)
    int*    counts   = (int*)alloc((size_t)N_NODES * 4);
    int*    ctrs     = (int*)alloc((size_t)256 * 4);
    float4* pos4     = (float4*)alloc((size_t)N_NODES * 16);
    float*  Pbuf     = (float*)alloc((size_t)2 * 256 * 16 * 4);
    double* Td_arr   = (double*)alloc((size_t)ICP_IT * B_GRAPHS * 12 * 8);
    int*    offs     = (int*)alloc((size_t)(N_NODES + 1) * 4);
    int*    cursor   = (int*)alloc((size_t)N_NODES * 4);
    int*    srcid    = (int*)alloc((size_t)E_EDGES * 4);
    float*  normv    = (float*)alloc((size_t)E_EDGES * 4);
    float*  dinv     = (float*)alloc((size_t)N_NODES * 4);
    unsigned short* xb  = (unsigned short*)alloc((size_t)N_NODES * F_IN * 2);
    unsigned short* W1b = (unsigned short*)alloc((size_t)F_IN * F_HID * 2);
    unsigned short* W2b = (unsigned short*)alloc((size_t)F_HID * F_HID * 2);
    unsigned short* W3b = (unsigned short*)alloc((size_t)F_HID * F_OUT * 2);
    unsigned short* bufA = (unsigned short*)alloc((size_t)N_NODES * F_HID * 2);
    unsigned short* bufB = (unsigned short*)alloc((size_t)N_NODES * F_HID * 2);
    unsigned short* bufC = (unsigned short*)alloc((size_t)N_NODES * F_HID * 2);
    float*  tpos     = (float*)alloc((size_t)N_NODES * 3 * 4);
    float*  chpart   = (float*)alloc((size_t)256 * 2 * 4);

    float* out_h       = (float*)d_out;
    float* out_aligned = out_h + (size_t)N_NODES * F_OUT;
    float* out_loss    = out_aligned + (size_t)N_NODES * 3;

    // 1: zero counts + ctrs (stream-ordered, replay-safe)
    hipMemsetAsync(counts, 0, (size_t)N_NODES * 4 + 256 * 4, stream);
    // 2: converts + pos4 + edge count
    k_prep<<<3648, 256, 0, stream>>>(x, xb, pos, pos4, W1, W2, W3, W1b, W2b, W3b, col, counts);
    // 3-4: CSR
    k_scan<<<1, 1024, 0, stream>>>(counts, offs, cursor, dinv);
    k_scatter<<<E_EDGES / 256, 256, 0, stream>>>(row, col, cursor, dinv, srcid, normv);

    // 5: layer1 aggregate (x bf16 -> bufA)
    k_agg128<0, 0><<<N_NODES / 2, 128, 0, stream>>>(xb, bufA, offs, srcid, normv, dinv,
            nullptr, 0, nullptr, nullptr, nullptr, nullptr);
    // 6: gemm1 + bias + relu
    {
        dim3 grid(F_HID / 64, N_NODES / 128);
        k_gemm_bf16<<<grid, 256, 0, stream>>>(bufA, W1b, b1, bufB, N_NODES, F_HID, F_IN, 1);
    }
    // 7: gemm2 (no bias)
    {
        dim3 grid(F_HID / 64, N_NODES / 128);
        k_gemm_bf16<<<grid, 256, 0, stream>>>(bufB, W2b, nullptr, bufC, N_NODES, F_HID, F_HID, 0);
    }
    // 8: layer2 aggregate + b2 + relu
    k_agg256<<<N_NODES / 2, 128, 0, stream>>>(bufC, bufA, offs, srcid, normv, dinv, b2, 1);
    // 9: gemm3
    {
        dim3 grid(F_OUT / 64, N_NODES / 128);
        k_gemm_bf16<<<grid, 256, 0, stream>>>(bufA, W3b, nullptr, bufB, N_NODES, F_OUT, F_HID, 0);
    }
    // 10: layer3 aggregate + b3 -> out_h (fp32), fused tpos
    k_agg128<1, 1><<<N_NODES / 2, 128, 0, stream>>>(bufB, out_h, offs, srcid, normv, dinv,
            b3, 0, Wt, bt, pos, tpos);

    // 11-20: ICP, one launch per iteration (kernel boundary = global sync)
    for (int j = 0; j < ICP_IT; ++j) {
        const float* Pin  = Pbuf + (size_t)((j + 1) & 1) * 256 * 16;  // prev (unused j=0)
        float*       Pout = Pbuf + (size_t)(j & 1) * 256 * 16;
        const double* TdIn = Td_arr + (size_t)(j > 0 ? j - 1 : 0) * B_GRAPHS * 12;
        double*       TdOut = Td_arr + (size_t)j * B_GRAPHS * 12;
        k_icp_nn<<<256, 512, 0, stream>>>(pos4, tpos, Pin, Pout, TdIn, TdOut, j);
    }
    // 21: T(10) + apply + chamfer + loss
    k_chamfer_all<<<256, 512, 0, stream>>>(pos4, tpos,
            Pbuf + (size_t)((ICP_IT - 1) & 1) * 256 * 16,
            Td_arr + (size_t)(ICP_IT - 1) * B_GRAPHS * 12,
            chpart, ctrs, out_aligned, out_loss);
}